// Round 2
// baseline (1059.378 us; speedup 1.0000x reference)
//
#include <hip/hip_runtime.h>
#include <hip/hip_bf16.h>

// Selective SSM (Mamba-style): B=2, L=1024, H=2048, E=2 -> d=4096, S=16, R=128.
// Round 2: runtime dtype detection (fp32 vs bf16 inputs) + canonicalize to bf16.
// Pipeline:
//  D)  detect input dtype (device-side flag in ws)
//  C)  canonicalize x + small tensors to bf16
//  T)  flag-aware transpose W_in, W_out, W_dt, W_x to N-major (k-contiguous)
//  K1) xz = x @ W_in                  (2048x8192x2048, bf16 MFMA)
//  K2) xc = silu(conv3(xp) + conv_b)
//  K3) x_dbl = xc @ W_x               (2048x160x4096, split-K=8, fp32 atomic out)
//  K4) dt = softplus(dt_in @ W_dt + b_dt)   (fp32 out, aliases W_inT)
//  K5) scan over L; y_gated = (scan_y + xc*D) * silu(z)   (bf16)
//  K6) out = y_gated @ W_out          (2048x2048x4096, flag-aware store to d_out)

using u16 = unsigned short;
typedef __bf16 bf16x8 __attribute__((ext_vector_type(8)));
typedef float f32x4 __attribute__((ext_vector_type(4)));

__device__ __forceinline__ float bf2f(u16 u) {
    union { unsigned int i; float f; } v; v.i = ((unsigned int)u) << 16; return v.f;
}
__device__ __forceinline__ u16 f2bf(float f) {
    union { float f; unsigned int i; } v; v.f = f;
    unsigned int x = v.i;
    return (u16)((x + 0x7FFFu + ((x >> 16) & 1u)) >> 16);   // RNE
}

// ---------------- dtype detection -------------------------------------------
// Even u16 indices of x: bf16 data -> exponent field in [100,145] ~100%;
// fp32 data -> even u16s are mantissa-low halves, ~18% plausible.
__global__ void detect_dtype(const u16* __restrict__ xraw, int* __restrict__ flag) {
    __shared__ int cnt[256];
    const int tid = threadIdx.x;
    int plausible = 0;
    for (int i = tid; i < 4096; i += 256) {
        const u16 v = xraw[2 * i];          // < 16 KB: in-bounds either dtype
        const int e = (v >> 7) & 0xFF;
        plausible += (e >= 100 && e <= 145) ? 1 : 0;
    }
    cnt[tid] = plausible;
    __syncthreads();
    for (int s = 128; s > 0; s >>= 1) {
        if (tid < s) cnt[tid] += cnt[tid + s];
        __syncthreads();
    }
    if (tid == 0) *flag = (cnt[0] > 2458) ? 1 : 0;   // >60% plausible -> bf16
}

// ---------------- canonicalize to bf16 --------------------------------------
__global__ void cvt_bf16(const void* __restrict__ src, u16* __restrict__ dst,
                         int n, const int* __restrict__ flag) {
    const int i = blockIdx.x * 256 + threadIdx.x;
    if (i >= n) return;
    if (*flag) dst[i] = ((const u16*)src)[i];
    else       dst[i] = f2bf(((const float*)src)[i]);
}

// ---------------- flag-aware transpose (32x32 tiles, dims %32==0) -----------
__global__ void transpose_any(const void* __restrict__ in, u16* __restrict__ out,
                              int R, int C, const int* __restrict__ flag) {
    __shared__ u16 tile[32][33];
    const int c0 = blockIdx.x * 32, r0 = blockIdx.y * 32;
    const int tx = threadIdx.x, ty = threadIdx.y;   // blockDim = (32, 8)
    const bool isbf = (*flag != 0);
#pragma unroll
    for (int i = 0; i < 4; i++) {
        const size_t idx = (size_t)(r0 + ty + i * 8) * C + c0 + tx;
        tile[ty + i * 8][tx] = isbf ? ((const u16*)in)[idx]
                                    : f2bf(((const float*)in)[idx]);
    }
    __syncthreads();
#pragma unroll
    for (int i = 0; i < 4; i++)
        out[(size_t)(c0 + ty + i * 8) * R + r0 + tx] = tile[tx][ty + i * 8];
}

// ---------------- generic bf16 MFMA GEMM:  C[M,N] = A[M,K] * Bt[N,K]^T -------
// MODE 0: bf16 store. MODE 1: flag-aware store (bf16 or fp32) for d_out.
// MODE 2: fp32 softplus(acc + bias[col]). MODE 4: fp32 atomicAdd.
template <int BM, int BN, int BK, int WR, int WC, int MT, int NT, int MODE>
__global__ __launch_bounds__(256) void gemm_bt(
    const u16* __restrict__ A, const u16* __restrict__ Bt,
    void* __restrict__ C, const u16* __restrict__ bias,
    const int* __restrict__ oflagp,
    int M, int N, int K)
{
    static_assert(BK == 32, "BK=32 (one 16x16x32 MFMA k-slab)");
    constexpr int LDSS = BK + 8;          // 40 u16 -> rows 16B aligned, ~2-way banks
    __shared__ u16 As[BM * LDSS];
    __shared__ u16 Bs[BN * LDSS];

    const int tid  = threadIdx.x;
    const int lane = tid & 63;
    const int wave = tid >> 6;
    const int wm = wave / WC, wn = wave % WC;

    const int m0 = blockIdx.y * BM;
    const int n0 = blockIdx.x * BN;
    const int Kchunk = K / gridDim.z;
    const int kbeg = blockIdx.z * Kchunk;
    const int kend = kbeg + Kchunk;

    int oflag = 1;
    if constexpr (MODE == 1) oflag = *oflagp;

    f32x4 acc[MT][NT];
#pragma unroll
    for (int mi = 0; mi < MT; mi++)
#pragma unroll
        for (int ni = 0; ni < NT; ni++)
            acc[mi][ni] = (f32x4){0.f, 0.f, 0.f, 0.f};

    const int koff = (lane >> 4) * 8;     // k-chunk within BK per lane
    const int arow = wm * MT * 16 + (lane & 15);
    const int brow = wn * NT * 16 + (lane & 15);

    for (int k0 = kbeg; k0 < kend; k0 += BK) {
        __syncthreads();
#pragma unroll
        for (int c = tid; c < BM * (BK / 8); c += 256) {
            const int row = c >> 2, kc = c & 3;
            uint4 v = *reinterpret_cast<const uint4*>(&A[(size_t)(m0 + row) * K + k0 + kc * 8]);
            *reinterpret_cast<uint4*>(&As[row * LDSS + kc * 8]) = v;
        }
#pragma unroll
        for (int c = tid; c < BN * (BK / 8); c += 256) {
            const int row = c >> 2, kc = c & 3;
            uint4 v = *reinterpret_cast<const uint4*>(&Bt[(size_t)(n0 + row) * K + k0 + kc * 8]);
            *reinterpret_cast<uint4*>(&Bs[row * LDSS + kc * 8]) = v;
        }
        __syncthreads();

        bf16x8 af[MT], bfr[NT];
#pragma unroll
        for (int mi = 0; mi < MT; mi++)
            af[mi] = *reinterpret_cast<const bf16x8*>(&As[(arow + mi * 16) * LDSS + koff]);
#pragma unroll
        for (int ni = 0; ni < NT; ni++)
            bfr[ni] = *reinterpret_cast<const bf16x8*>(&Bs[(brow + ni * 16) * LDSS + koff]);
#pragma unroll
        for (int mi = 0; mi < MT; mi++)
#pragma unroll
            for (int ni = 0; ni < NT; ni++)
                acc[mi][ni] = __builtin_amdgcn_mfma_f32_16x16x32_bf16(
                    af[mi], bfr[ni], acc[mi][ni], 0, 0, 0);
    }

    // epilogue: D[row=(lane>>4)*4+r][col=lane&15]  (m89-verified layout)
    const int rb = m0 + wm * MT * 16 + ((lane >> 4) << 2);
    const int cb = n0 + wn * NT * 16 + (lane & 15);
#pragma unroll
    for (int mi = 0; mi < MT; mi++) {
#pragma unroll
        for (int ni = 0; ni < NT; ni++) {
            const int col = cb + ni * 16;
#pragma unroll
            for (int r = 0; r < 4; r++) {
                const int row = rb + mi * 16 + r;
                const float v = acc[mi][ni][r];
                if constexpr (MODE == 0) {
                    ((u16*)C)[(size_t)row * N + col] = f2bf(v);
                } else if constexpr (MODE == 1) {
                    if (oflag) ((u16*)C)[(size_t)row * N + col] = f2bf(v);
                    else       ((float*)C)[(size_t)row * N + col] = v;
                } else if constexpr (MODE == 2) {
                    const float x = v + bf2f(bias[col]);
                    const float sp = (x > 20.f) ? x : log1pf(__expf(x));
                    ((float*)C)[(size_t)row * N + col] = sp;
                } else if constexpr (MODE == 4) {
                    atomicAdd(((float*)C) + (size_t)row * N + col, v);
                }
            }
        }
    }
}

// ---------------- depthwise conv3 ("same" pad per batch) + bias + silu ------
__global__ void conv_silu(const u16* __restrict__ xz, const u16* __restrict__ conv_w,
                          const u16* __restrict__ conv_b, u16* __restrict__ xc) {
    const int idx = blockIdx.x * 256 + threadIdx.x;    // 2048*4096
    const int row = idx >> 12, c = idx & 4095;
    const int l = row & 1023;
    const float w0 = bf2f(conv_w[c * 3 + 0]);
    const float w1 = bf2f(conv_w[c * 3 + 1]);
    const float w2 = bf2f(conv_w[c * 3 + 2]);
    const float x0 = bf2f(xz[(size_t)row * 8192 + c]);
    const float xm = (l > 0)    ? bf2f(xz[(size_t)(row - 1) * 8192 + c]) : 0.f;
    const float xp = (l < 1023) ? bf2f(xz[(size_t)(row + 1) * 8192 + c]) : 0.f;
    float v = w0 * xm + w1 * x0 + w2 * xp + bf2f(conv_b[c]);
    v = v / (1.f + __expf(-v));                        // silu
    xc[(size_t)row * 4096 + c] = f2bf(v);
}

// ---------------- x_dbl[:, :128] -> bf16 for the dt GEMM --------------------
__global__ void cvt_dtin(const float* __restrict__ x_dbl, u16* __restrict__ dtin) {
    const int idx = blockIdx.x * 256 + threadIdx.x;    // 2048*128
    const int row = idx >> 7, c = idx & 127;
    dtin[idx] = f2bf(x_dbl[(size_t)row * 160 + c]);
}

// ---------------- selective scan + gating -----------------------------------
// lane = (s<<2) | c_local : 4 channels/wave, 16 states/channel. 512 blocks.
__global__ __launch_bounds__(256) void scan_kernel(
    const float* __restrict__ dt, const u16* __restrict__ xc,
    const float* __restrict__ x_dbl, const u16* __restrict__ xz,
    const u16* __restrict__ A_log, const u16* __restrict__ Dp,
    u16* __restrict__ yg)
{
    const int tid = threadIdx.x;
    const int lane = tid & 63, wave = tid >> 6;
    const int blk = blockIdx.x;              // 0..511
    const int b = blk >> 8;                  // batch
    const int cg = blk & 255;
    const int c_local = lane & 3, s = lane >> 2;
    const int ch = cg * 16 + wave * 4 + c_local;

    const float A_s = -__expf(bf2f(A_log[ch * 16 + s]));
    const float D_ch = bf2f(Dp[ch]);
    float h = 0.f, ybuf = 0.f;

    const size_t row0 = (size_t)b * 1024;
    float dt_v = dt[row0 * 4096 + ch];
    float u_v  = bf2f(xc[row0 * 4096 + ch]);
    float Bv   = x_dbl[row0 * 160 + 128 + s];
    float Cv   = x_dbl[row0 * 160 + 144 + s];
    float z_v  = bf2f(xz[row0 * 8192 + 4096 + ch]);

    for (int t = 0; t < 1024; t++) {
        const int tn = (t + 1 < 1024) ? t + 1 : t;
        const size_t rn = row0 + tn;
        const float dt_n = dt[rn * 4096 + ch];
        const float u_n  = bf2f(xc[rn * 4096 + ch]);
        const float B_n  = x_dbl[rn * 160 + 128 + s];
        const float C_n  = x_dbl[rn * 160 + 144 + s];
        const float z_n  = bf2f(xz[rn * 8192 + 4096 + ch]);

        const float dA = __expf(dt_v * A_s);
        h = dA * h + dt_v * Bv * u_v;
        float p = h * Cv;
        p += __shfl_xor(p, 4);
        p += __shfl_xor(p, 8);
        p += __shfl_xor(p, 16);
        p += __shfl_xor(p, 32);              // all 16 s-lanes now hold the sum
        const float silu_z = z_v / (1.f + __expf(-z_v));
        const float yv = (p + u_v * D_ch) * silu_z;
        ybuf = (s == (t & 15)) ? yv : ybuf;
        if ((t & 15) == 15) {
            const size_t orow = row0 + (size_t)(t - 15 + s);
            yg[orow * 4096 + ch] = f2bf(ybuf);
        }
        dt_v = dt_n; u_v = u_n; Bv = B_n; Cv = C_n; z_v = z_n;
    }
}

extern "C" void kernel_launch(void* const* d_in, const int* in_sizes, int n_in,
                              void* d_out, int out_size, void* d_ws, size_t ws_size,
                              hipStream_t stream)
{
    const void* x_raw      = d_in[0];   // (2,1024,2048)
    const void* W_in_raw   = d_in[1];   // (2048,8192)
    const void* conv_w_raw = d_in[2];   // (4096,1,3)
    const void* conv_b_raw = d_in[3];   // (4096)
    const void* W_x_raw    = d_in[4];   // (4096,160)
    const void* W_dt_raw   = d_in[5];   // (128,4096)
    const void* b_dt_raw   = d_in[6];   // (4096)
    const void* A_log_raw  = d_in[7];   // (4096,16)
    const void* D_raw      = d_in[8];   // (4096)
    const void* W_out_raw  = d_in[9];   // (4096,2048)

    char* ws = (char*)d_ws;
    size_t off = 0;
    auto alloc = [&](size_t bytes) { char* p = ws + off; off += (bytes + 255) & ~(size_t)255; return p; };
    int*   flag   = (int*)  alloc(4);
    u16*   W_inT  = (u16*)  alloc(8192ULL * 2048 * 2);   // 32 MB (aliased by dt fp32 after K1)
    u16*   W_outT = (u16*)  alloc(2048ULL * 4096 * 2);   // 16 MB
    u16*   W_dtT  = (u16*)  alloc(4096ULL * 128 * 2);    // 1 MB
    u16*   W_xT   = (u16*)  alloc(160ULL * 4096 * 2);    // 1.25 MB
    u16*   xz     = (u16*)  alloc(2048ULL * 8192 * 2);   // 32 MB
    u16*   xc     = (u16*)  alloc(2048ULL * 4096 * 2);   // 16 MB
    float* x_dbl  = (float*)alloc(2048ULL * 160 * 4);    // 1.25 MB
    u16*   dtin   = (u16*)  alloc(2048ULL * 128 * 2);    // 0.5 MB
    u16*   yg     = (u16*)  alloc(2048ULL * 4096 * 2);   // 16 MB
    u16*   xcan   = (u16*)  alloc(2048ULL * 2048 * 2);   // 8 MB canonical bf16 x
    u16*   cw_c   = (u16*)  alloc(12288 * 2);
    u16*   cb_c   = (u16*)  alloc(4096 * 2);
    u16*   bdt_c  = (u16*)  alloc(4096 * 2);
    u16*   Alog_c = (u16*)  alloc(65536 * 2);
    u16*   D_c    = (u16*)  alloc(4096 * 2);
    float* dtv    = (float*)W_inT;   // alias: W_inT dead after K1; 2048*4096*4 = 32 MB exact

    // D) dtype flag
    detect_dtype<<<1, 256, 0, stream>>>((const u16*)x_raw, flag);

    // C) canonicalize
    cvt_bf16<<<(2048 * 2048) / 256, 256, 0, stream>>>(x_raw, xcan, 2048 * 2048, flag);
    cvt_bf16<<<48, 256, 0, stream>>>(conv_w_raw, cw_c, 12288, flag);
    cvt_bf16<<<16, 256, 0, stream>>>(conv_b_raw, cb_c, 4096, flag);
    cvt_bf16<<<16, 256, 0, stream>>>(b_dt_raw, bdt_c, 4096, flag);
    cvt_bf16<<<256, 256, 0, stream>>>(A_log_raw, Alog_c, 65536, flag);
    cvt_bf16<<<16, 256, 0, stream>>>(D_raw, D_c, 4096, flag);

    // T) transposes (flag-aware load)
    const dim3 tb(32, 8);
    transpose_any<<<dim3(8192 / 32, 2048 / 32), tb, 0, stream>>>(W_in_raw,  W_inT,  2048, 8192, flag);
    transpose_any<<<dim3(2048 / 32, 4096 / 32), tb, 0, stream>>>(W_out_raw, W_outT, 4096, 2048, flag);
    transpose_any<<<dim3(4096 / 32, 128 / 32),  tb, 0, stream>>>(W_dt_raw,  W_dtT,  128,  4096, flag);
    transpose_any<<<dim3(160 / 32, 4096 / 32),  tb, 0, stream>>>(W_x_raw,   W_xT,   4096, 160,  flag);

    // K1: xz = x @ W_in   (M=2048, N=8192, K=2048)
    gemm_bt<128, 128, 32, 2, 2, 4, 4, 0>
        <<<dim3(8192 / 128, 2048 / 128, 1), 256, 0, stream>>>(xcan, W_inT, xz, nullptr, nullptr, 2048, 8192, 2048);

    // K2: conv + bias + silu
    conv_silu<<<(2048 * 4096) / 256, 256, 0, stream>>>(xz, cw_c, cb_c, xc);

    // K3: x_dbl = xc @ W_x   (M=2048, N=160, K=4096, split-K=8, atomic fp32)
    hipMemsetAsync(x_dbl, 0, 2048ULL * 160 * 4, stream);
    gemm_bt<64, 160, 32, 4, 1, 1, 10, 4>
        <<<dim3(1, 2048 / 64, 8), 256, 0, stream>>>(xc, W_xT, x_dbl, nullptr, nullptr, 2048, 160, 4096);

    cvt_dtin<<<(2048 * 128) / 256, 256, 0, stream>>>(x_dbl, dtin);

    // K4: dt = softplus(dtin @ W_dt + b_dt)   (M=2048, N=4096, K=128, fp32 out)
    gemm_bt<128, 128, 32, 2, 2, 4, 4, 2>
        <<<dim3(4096 / 128, 2048 / 128, 1), 256, 0, stream>>>(dtin, W_dtT, dtv, bdt_c, nullptr, 2048, 4096, 128);

    // K5: selective scan + skip + gate
    scan_kernel<<<512, 256, 0, stream>>>(dtv, xc, x_dbl, xz, Alog_c, D_c, yg);

    // K6: out = yg @ W_out   (M=2048, N=2048, K=4096), flag-aware store
    gemm_bt<128, 128, 32, 2, 2, 4, 4, 1>
        <<<dim3(2048 / 128, 2048 / 128, 1), 256, 0, stream>>>(yg, W_outT, d_out, nullptr, flag, 2048, 2048, 4096);
}

// Round 3
// 784.900 us; speedup vs baseline: 1.3497x; 1.3497x over previous
//
#include <hip/hip_runtime.h>
#include <hip/hip_bf16.h>

// Selective SSM (Mamba-style): B=2, L=1024, H=2048, E=2 -> d=4096, S=16, R=128.
// Round 3: chunked selective scan (16 chunks x 64 steps) for 16x scan parallelism.
// Pipeline:
//  D)  detect input dtype (fp32 vs bf16), canonicalize to bf16
//  T)  transpose W_in, W_out, W_dt, W_x to N-major
//  K1) xz = x @ W_in                  (2048x8192x2048, bf16 MFMA)
//  K2) xc = silu(conv3(xp) + conv_b)
//  K3) x_dbl = xc @ W_x               (2048x160x4096, split-K=8, fp32 atomic)
//  K4) dt = softplus(dt_in @ W_dt + b_dt)   (fp32, aliases W_inT)
//  S1) per-chunk local scan (h_in=0): P = prod dA, h_loc_end
//  S2) combine chunk summaries -> h_in per chunk (16 serial steps)
//  S3) per-chunk rescan with h_in; y_gated = (y + xc*D) * silu(z)
//  K6) out = y_gated @ W_out          (2048x2048x4096, flag-aware store)

using u16 = unsigned short;
typedef __bf16 bf16x8 __attribute__((ext_vector_type(8)));
typedef float f32x4 __attribute__((ext_vector_type(4)));

#define NCHUNK 16
#define CLEN   64

__device__ __forceinline__ float bf2f(u16 u) {
    union { unsigned int i; float f; } v; v.i = ((unsigned int)u) << 16; return v.f;
}
__device__ __forceinline__ u16 f2bf(float f) {
    union { float f; unsigned int i; } v; v.f = f;
    unsigned int x = v.i;
    return (u16)((x + 0x7FFFu + ((x >> 16) & 1u)) >> 16);   // RNE
}

// fp32 scratch carved out of the dead xp-column half of xz (rows x 8192 u16;
// cols 0..4095 are dead after conv). Row r holds 2048 fp32 slots.
// h_loc: rows 0..1023, h_in: rows 1024..2047. i in [0, 2^21).
__device__ __forceinline__ float* hloc_ptr(u16* xzbase, int i) {
    return reinterpret_cast<float*>(xzbase + (size_t)(i >> 11) * 8192) + (i & 2047);
}
__device__ __forceinline__ float* hin_ptr(u16* xzbase, int i) {
    return reinterpret_cast<float*>(xzbase + (size_t)((i >> 11) + 1024) * 8192) + (i & 2047);
}

// ---------------- dtype detection -------------------------------------------
__global__ void detect_dtype(const u16* __restrict__ xraw, int* __restrict__ flag) {
    __shared__ int cnt[256];
    const int tid = threadIdx.x;
    int plausible = 0;
    for (int i = tid; i < 4096; i += 256) {
        const u16 v = xraw[2 * i];
        const int e = (v >> 7) & 0xFF;
        plausible += (e >= 100 && e <= 145) ? 1 : 0;
    }
    cnt[tid] = plausible;
    __syncthreads();
    for (int s = 128; s > 0; s >>= 1) {
        if (tid < s) cnt[tid] += cnt[tid + s];
        __syncthreads();
    }
    if (tid == 0) *flag = (cnt[0] > 2458) ? 1 : 0;
}

// ---------------- canonicalize to bf16 --------------------------------------
__global__ void cvt_bf16(const void* __restrict__ src, u16* __restrict__ dst,
                         int n, const int* __restrict__ flag) {
    const int i = blockIdx.x * 256 + threadIdx.x;
    if (i >= n) return;
    if (*flag) dst[i] = ((const u16*)src)[i];
    else       dst[i] = f2bf(((const float*)src)[i]);
}

// ---------------- flag-aware transpose (32x32 tiles, dims %32==0) -----------
__global__ void transpose_any(const void* __restrict__ in, u16* __restrict__ out,
                              int R, int C, const int* __restrict__ flag) {
    __shared__ u16 tile[32][33];
    const int c0 = blockIdx.x * 32, r0 = blockIdx.y * 32;
    const int tx = threadIdx.x, ty = threadIdx.y;   // blockDim = (32, 8)
    const bool isbf = (*flag != 0);
#pragma unroll
    for (int i = 0; i < 4; i++) {
        const size_t idx = (size_t)(r0 + ty + i * 8) * C + c0 + tx;
        tile[ty + i * 8][tx] = isbf ? ((const u16*)in)[idx]
                                    : f2bf(((const float*)in)[idx]);
    }
    __syncthreads();
#pragma unroll
    for (int i = 0; i < 4; i++)
        out[(size_t)(c0 + ty + i * 8) * R + r0 + tx] = tile[tx][ty + i * 8];
}

// ---------------- generic bf16 MFMA GEMM:  C[M,N] = A[M,K] * Bt[N,K]^T -------
// MODE 0: bf16 store. MODE 1: flag-aware store (bf16 or fp32) for d_out.
// MODE 2: fp32 softplus(acc + bias[col]). MODE 4: fp32 atomicAdd.
template <int BM, int BN, int BK, int WR, int WC, int MT, int NT, int MODE>
__global__ __launch_bounds__(256) void gemm_bt(
    const u16* __restrict__ A, const u16* __restrict__ Bt,
    void* __restrict__ C, const u16* __restrict__ bias,
    const int* __restrict__ oflagp,
    int M, int N, int K)
{
    static_assert(BK == 32, "BK=32 (one 16x16x32 MFMA k-slab)");
    constexpr int LDSS = BK + 8;
    __shared__ u16 As[BM * LDSS];
    __shared__ u16 Bs[BN * LDSS];

    const int tid  = threadIdx.x;
    const int lane = tid & 63;
    const int wave = tid >> 6;
    const int wm = wave / WC, wn = wave % WC;

    const int m0 = blockIdx.y * BM;
    const int n0 = blockIdx.x * BN;
    const int Kchunk = K / gridDim.z;
    const int kbeg = blockIdx.z * Kchunk;
    const int kend = kbeg + Kchunk;

    int oflag = 1;
    if constexpr (MODE == 1) oflag = *oflagp;

    f32x4 acc[MT][NT];
#pragma unroll
    for (int mi = 0; mi < MT; mi++)
#pragma unroll
        for (int ni = 0; ni < NT; ni++)
            acc[mi][ni] = (f32x4){0.f, 0.f, 0.f, 0.f};

    const int koff = (lane >> 4) * 8;
    const int arow = wm * MT * 16 + (lane & 15);
    const int brow = wn * NT * 16 + (lane & 15);

    for (int k0 = kbeg; k0 < kend; k0 += BK) {
        __syncthreads();
#pragma unroll
        for (int c = tid; c < BM * (BK / 8); c += 256) {
            const int row = c >> 2, kc = c & 3;
            uint4 v = *reinterpret_cast<const uint4*>(&A[(size_t)(m0 + row) * K + k0 + kc * 8]);
            *reinterpret_cast<uint4*>(&As[row * LDSS + kc * 8]) = v;
        }
#pragma unroll
        for (int c = tid; c < BN * (BK / 8); c += 256) {
            const int row = c >> 2, kc = c & 3;
            uint4 v = *reinterpret_cast<const uint4*>(&Bt[(size_t)(n0 + row) * K + k0 + kc * 8]);
            *reinterpret_cast<uint4*>(&Bs[row * LDSS + kc * 8]) = v;
        }
        __syncthreads();

        bf16x8 af[MT], bfr[NT];
#pragma unroll
        for (int mi = 0; mi < MT; mi++)
            af[mi] = *reinterpret_cast<const bf16x8*>(&As[(arow + mi * 16) * LDSS + koff]);
#pragma unroll
        for (int ni = 0; ni < NT; ni++)
            bfr[ni] = *reinterpret_cast<const bf16x8*>(&Bs[(brow + ni * 16) * LDSS + koff]);
#pragma unroll
        for (int mi = 0; mi < MT; mi++)
#pragma unroll
            for (int ni = 0; ni < NT; ni++)
                acc[mi][ni] = __builtin_amdgcn_mfma_f32_16x16x32_bf16(
                    af[mi], bfr[ni], acc[mi][ni], 0, 0, 0);
    }

    const int rb = m0 + wm * MT * 16 + ((lane >> 4) << 2);
    const int cb = n0 + wn * NT * 16 + (lane & 15);
#pragma unroll
    for (int mi = 0; mi < MT; mi++) {
#pragma unroll
        for (int ni = 0; ni < NT; ni++) {
            const int col = cb + ni * 16;
#pragma unroll
            for (int r = 0; r < 4; r++) {
                const int row = rb + mi * 16 + r;
                const float v = acc[mi][ni][r];
                if constexpr (MODE == 0) {
                    ((u16*)C)[(size_t)row * N + col] = f2bf(v);
                } else if constexpr (MODE == 1) {
                    if (oflag) ((u16*)C)[(size_t)row * N + col] = f2bf(v);
                    else       ((float*)C)[(size_t)row * N + col] = v;
                } else if constexpr (MODE == 2) {
                    const float x = v + bf2f(bias[col]);
                    const float sp = (x > 20.f) ? x : log1pf(__expf(x));
                    ((float*)C)[(size_t)row * N + col] = sp;
                } else if constexpr (MODE == 4) {
                    atomicAdd(((float*)C) + (size_t)row * N + col, v);
                }
            }
        }
    }
}

// ---------------- depthwise conv3 + bias + silu -----------------------------
__global__ void conv_silu(const u16* __restrict__ xz, const u16* __restrict__ conv_w,
                          const u16* __restrict__ conv_b, u16* __restrict__ xc) {
    const int idx = blockIdx.x * 256 + threadIdx.x;    // 2048*4096
    const int row = idx >> 12, c = idx & 4095;
    const int l = row & 1023;
    const float w0 = bf2f(conv_w[c * 3 + 0]);
    const float w1 = bf2f(conv_w[c * 3 + 1]);
    const float w2 = bf2f(conv_w[c * 3 + 2]);
    const float x0 = bf2f(xz[(size_t)row * 8192 + c]);
    const float xm = (l > 0)    ? bf2f(xz[(size_t)(row - 1) * 8192 + c]) : 0.f;
    const float xp = (l < 1023) ? bf2f(xz[(size_t)(row + 1) * 8192 + c]) : 0.f;
    float v = w0 * xm + w1 * x0 + w2 * xp + bf2f(conv_b[c]);
    v = v / (1.f + __expf(-v));
    xc[(size_t)row * 4096 + c] = f2bf(v);
}

// ---------------- x_dbl[:, :128] -> bf16 ------------------------------------
__global__ void cvt_dtin(const float* __restrict__ x_dbl, u16* __restrict__ dtin) {
    const int idx = blockIdx.x * 256 + threadIdx.x;    // 2048*128
    const int row = idx >> 7, c = idx & 127;
    dtin[idx] = f2bf(x_dbl[(size_t)row * 160 + c]);
}

// ---------------- S1: per-chunk local scan (h_in = 0) -----------------------
// grid (NCHUNK, 256, 2); lane = (s<<2)|c_local, 4 ch/wave, 16 ch/block.
__global__ __launch_bounds__(256) void scan_p1(
    const float* __restrict__ dt, const u16* __restrict__ xc,
    const float* __restrict__ x_dbl, const u16* __restrict__ A_log,
    float* __restrict__ Parr, u16* __restrict__ xzbase)
{
    const int tid = threadIdx.x;
    const int lane = tid & 63, wave = tid >> 6;
    const int nc = blockIdx.x, cg = blockIdx.y, b = blockIdx.z;
    const int c_local = lane & 3, s = lane >> 2;
    const int ch = cg * 16 + wave * 4 + c_local;

    const float A_s = -__expf(bf2f(A_log[ch * 16 + s]));
    float h = 0.f, P = 1.f;
    const size_t row0 = (size_t)b * 1024 + nc * CLEN;

    float dt_v = dt[row0 * 4096 + ch];
    float u_v  = bf2f(xc[row0 * 4096 + ch]);
    float Bv   = x_dbl[row0 * 160 + 128 + s];

    for (int t = 0; t < CLEN; t++) {
        const int tn = (t + 1 < CLEN) ? t + 1 : t;
        const size_t rn = row0 + tn;
        const float dt_n = dt[rn * 4096 + ch];
        const float u_n  = bf2f(xc[rn * 4096 + ch]);
        const float B_n  = x_dbl[rn * 160 + 128 + s];
        const float dA = __expf(dt_v * A_s);
        P *= dA;
        h = dA * h + dt_v * Bv * u_v;
        dt_v = dt_n; u_v = u_n; Bv = B_n;
    }
    const int i = (((b * NCHUNK + nc) * 4096) + ch) * 16 + s;
    Parr[i] = P;
    *hloc_ptr(xzbase, i) = h;
}

// ---------------- S2: combine chunk summaries -> h_in -----------------------
// 512 blocks x 256: b = blk>>8, cg = blk&255.
__global__ __launch_bounds__(256) void scan_p2(
    const float* __restrict__ Parr, u16* __restrict__ xzbase)
{
    const int tid = threadIdx.x;
    const int lane = tid & 63, wave = tid >> 6;
    const int blk = blockIdx.x;
    const int b = blk >> 8, cg = blk & 255;
    const int c_local = lane & 3, s = lane >> 2;
    const int ch = cg * 16 + wave * 4 + c_local;

    float Pv[NCHUNK], hl[NCHUNK];
#pragma unroll
    for (int c = 0; c < NCHUNK; c++) {
        const int i = (((b * NCHUNK + c) * 4096) + ch) * 16 + s;
        Pv[c] = Parr[i];
        hl[c] = *hloc_ptr(xzbase, i);
    }
    float hin = 0.f;
#pragma unroll
    for (int c = 0; c < NCHUNK; c++) {
        const int i = (((b * NCHUNK + c) * 4096) + ch) * 16 + s;
        *hin_ptr(xzbase, i) = hin;
        hin = Pv[c] * hin + hl[c];
    }
}

// ---------------- S3: rescan with h_in; emit gated y ------------------------
__global__ __launch_bounds__(256) void scan_p3(
    const float* __restrict__ dt, const u16* __restrict__ xc,
    const float* __restrict__ x_dbl, const u16* __restrict__ xz,
    const u16* __restrict__ A_log, const u16* __restrict__ Dp,
    u16* __restrict__ yg, u16* __restrict__ xzbase)
{
    const int tid = threadIdx.x;
    const int lane = tid & 63, wave = tid >> 6;
    const int nc = blockIdx.x, cg = blockIdx.y, b = blockIdx.z;
    const int c_local = lane & 3, s = lane >> 2;
    const int ch = cg * 16 + wave * 4 + c_local;

    const float A_s = -__expf(bf2f(A_log[ch * 16 + s]));
    const float D_ch = bf2f(Dp[ch]);
    const int i0 = (((b * NCHUNK + nc) * 4096) + ch) * 16 + s;
    float h = *hin_ptr(xzbase, i0);
    float ybuf = 0.f;
    const size_t row0 = (size_t)b * 1024 + nc * CLEN;

    float dt_v = dt[row0 * 4096 + ch];
    float u_v  = bf2f(xc[row0 * 4096 + ch]);
    float Bv   = x_dbl[row0 * 160 + 128 + s];
    float Cv   = x_dbl[row0 * 160 + 144 + s];
    float z_v  = bf2f(xz[row0 * 8192 + 4096 + ch]);

    for (int t = 0; t < CLEN; t++) {
        const int tn = (t + 1 < CLEN) ? t + 1 : t;
        const size_t rn = row0 + tn;
        const float dt_n = dt[rn * 4096 + ch];
        const float u_n  = bf2f(xc[rn * 4096 + ch]);
        const float B_n  = x_dbl[rn * 160 + 128 + s];
        const float C_n  = x_dbl[rn * 160 + 144 + s];
        const float z_n  = bf2f(xz[rn * 8192 + 4096 + ch]);

        const float dA = __expf(dt_v * A_s);
        h = dA * h + dt_v * Bv * u_v;
        float p = h * Cv;
        p += __shfl_xor(p, 4);
        p += __shfl_xor(p, 8);
        p += __shfl_xor(p, 16);
        p += __shfl_xor(p, 32);
        const float silu_z = z_v / (1.f + __expf(-z_v));
        const float yv = (p + u_v * D_ch) * silu_z;
        ybuf = (s == (t & 15)) ? yv : ybuf;
        if ((t & 15) == 15) {
            const size_t orow = row0 + (size_t)(t - 15 + s);
            yg[orow * 4096 + ch] = f2bf(ybuf);
        }
        dt_v = dt_n; u_v = u_n; Bv = B_n; Cv = C_n; z_v = z_n;
    }
}

extern "C" void kernel_launch(void* const* d_in, const int* in_sizes, int n_in,
                              void* d_out, int out_size, void* d_ws, size_t ws_size,
                              hipStream_t stream)
{
    const void* x_raw      = d_in[0];   // (2,1024,2048)
    const void* W_in_raw   = d_in[1];   // (2048,8192)
    const void* conv_w_raw = d_in[2];   // (4096,1,3)
    const void* conv_b_raw = d_in[3];   // (4096)
    const void* W_x_raw    = d_in[4];   // (4096,160)
    const void* W_dt_raw   = d_in[5];   // (128,4096)
    const void* b_dt_raw   = d_in[6];   // (4096)
    const void* A_log_raw  = d_in[7];   // (4096,16)
    const void* D_raw      = d_in[8];   // (4096)
    const void* W_out_raw  = d_in[9];   // (4096,2048)

    char* ws = (char*)d_ws;
    size_t off = 0;
    auto alloc = [&](size_t bytes) { char* p = ws + off; off += (bytes + 255) & ~(size_t)255; return p; };
    int*   flag   = (int*)  alloc(4);
    u16*   W_inT  = (u16*)  alloc(8192ULL * 2048 * 2);   // 32 MB (aliased by dt fp32 after K1)
    u16*   W_outT = (u16*)  alloc(2048ULL * 4096 * 2);   // 16 MB
    u16*   W_dtT  = (u16*)  alloc(4096ULL * 128 * 2);    // 1 MB
    u16*   W_xT   = (u16*)  alloc(160ULL * 4096 * 2);    // 1.25 MB
    u16*   xz     = (u16*)  alloc(2048ULL * 8192 * 2);   // 32 MB (xp half reused as h_loc/h_in)
    u16*   xc     = (u16*)  alloc(2048ULL * 4096 * 2);   // 16 MB
    float* x_dbl  = (float*)alloc(2048ULL * 160 * 4);    // 1.25 MB
    u16*   dtin   = (u16*)  alloc(2048ULL * 128 * 2);    // 0.5 MB
    u16*   yg     = (u16*)  alloc(2048ULL * 4096 * 2);   // 16 MB
    u16*   xcan   = (u16*)  alloc(2048ULL * 2048 * 2);   // 8 MB (reused as Parr fp32)
    u16*   cw_c   = (u16*)  alloc(12288 * 2);
    u16*   cb_c   = (u16*)  alloc(4096 * 2);
    u16*   bdt_c  = (u16*)  alloc(4096 * 2);
    u16*   Alog_c = (u16*)  alloc(65536 * 2);
    u16*   D_c    = (u16*)  alloc(4096 * 2);
    float* dtv    = (float*)W_inT;   // alias: W_inT dead after K1 (32 MB exact)
    float* Parr   = (float*)xcan;    // alias: xcan dead after K1 (8 MB exact)

    // D) dtype flag + canonicalize
    detect_dtype<<<1, 256, 0, stream>>>((const u16*)x_raw, flag);
    cvt_bf16<<<(2048 * 2048) / 256, 256, 0, stream>>>(x_raw, xcan, 2048 * 2048, flag);
    cvt_bf16<<<48, 256, 0, stream>>>(conv_w_raw, cw_c, 12288, flag);
    cvt_bf16<<<16, 256, 0, stream>>>(conv_b_raw, cb_c, 4096, flag);
    cvt_bf16<<<16, 256, 0, stream>>>(b_dt_raw, bdt_c, 4096, flag);
    cvt_bf16<<<256, 256, 0, stream>>>(A_log_raw, Alog_c, 65536, flag);
    cvt_bf16<<<16, 256, 0, stream>>>(D_raw, D_c, 4096, flag);

    // T) transposes
    const dim3 tb(32, 8);
    transpose_any<<<dim3(8192 / 32, 2048 / 32), tb, 0, stream>>>(W_in_raw,  W_inT,  2048, 8192, flag);
    transpose_any<<<dim3(2048 / 32, 4096 / 32), tb, 0, stream>>>(W_out_raw, W_outT, 4096, 2048, flag);
    transpose_any<<<dim3(4096 / 32, 128 / 32),  tb, 0, stream>>>(W_dt_raw,  W_dtT,  128,  4096, flag);
    transpose_any<<<dim3(160 / 32, 4096 / 32),  tb, 0, stream>>>(W_x_raw,   W_xT,   4096, 160,  flag);

    // K1: xz = x @ W_in   (M=2048, N=8192, K=2048)
    gemm_bt<128, 128, 32, 2, 2, 4, 4, 0>
        <<<dim3(8192 / 128, 2048 / 128, 1), 256, 0, stream>>>(xcan, W_inT, xz, nullptr, nullptr, 2048, 8192, 2048);

    // K2: conv + bias + silu
    conv_silu<<<(2048 * 4096) / 256, 256, 0, stream>>>(xz, cw_c, cb_c, xc);

    // K3: x_dbl = xc @ W_x   (split-K=8, atomic fp32)
    hipMemsetAsync(x_dbl, 0, 2048ULL * 160 * 4, stream);
    gemm_bt<64, 160, 32, 4, 1, 1, 10, 4>
        <<<dim3(1, 2048 / 64, 8), 256, 0, stream>>>(xc, W_xT, x_dbl, nullptr, nullptr, 2048, 160, 4096);

    cvt_dtin<<<(2048 * 128) / 256, 256, 0, stream>>>(x_dbl, dtin);

    // K4: dt = softplus(dtin @ W_dt + b_dt)   (fp32 out)
    gemm_bt<128, 128, 32, 2, 2, 4, 4, 2>
        <<<dim3(4096 / 128, 2048 / 128, 1), 256, 0, stream>>>(dtin, W_dtT, dtv, bdt_c, nullptr, 2048, 4096, 128);

    // S1/S2/S3: chunked selective scan + gating
    scan_p1<<<dim3(NCHUNK, 256, 2), 256, 0, stream>>>(dtv, xc, x_dbl, Alog_c, Parr, xz);
    scan_p2<<<512, 256, 0, stream>>>(Parr, xz);
    scan_p3<<<dim3(NCHUNK, 256, 2), 256, 0, stream>>>(dtv, xc, x_dbl, xz, Alog_c, D_c, yg, xz);

    // K6: out = yg @ W_out   (M=2048, N=2048, K=4096), flag-aware store
    gemm_bt<128, 128, 32, 2, 2, 4, 4, 1>
        <<<dim3(2048 / 128, 2048 / 128, 1), 256, 0, stream>>>(yg, W_outT, d_out, nullptr, flag, 2048, 2048, 4096);
}

// Round 4
// 719.983 us; speedup vs baseline: 1.4714x; 1.0902x over previous
//
#include <hip/hip_runtime.h>
#include <hip/hip_bf16.h>

// Selective SSM (Mamba-style): B=2, L=1024, H=2048, E=2 -> d=4096, S=16, R=128.
// Round 4: GEMM staging via __builtin_amdgcn_global_load_lds width=16
// (m93->m97 ladder step), lane-ordered unpadded LDS tiles.
// Pipeline:
//  D)  detect input dtype (fp32 vs bf16), canonicalize to bf16
//  T)  transpose W_in, W_out, W_dt, W_x to N-major
//  K1) xz = x @ W_in                  (2048x8192x2048, bf16 MFMA)
//  K2) xc = silu(conv3(xp) + conv_b)
//  K3) x_dbl = xc @ W_x               (2048x160x4096, split-K=8, fp32 atomic)
//  K4) dt = softplus(dt_in @ W_dt + b_dt)   (fp32, aliases W_inT)
//  S1) per-chunk local scan (h_in=0): P = prod dA, h_loc_end
//  S2) combine chunk summaries -> h_in per chunk (16 serial steps)
//  S3) per-chunk rescan with h_in; y_gated = (y + xc*D) * silu(z)
//  K6) out = y_gated @ W_out          (2048x2048x4096, flag-aware store)

using u16 = unsigned short;
typedef __bf16 bf16x8 __attribute__((ext_vector_type(8)));
typedef float f32x4 __attribute__((ext_vector_type(4)));

#define NCHUNK 16
#define CLEN   64

__device__ __forceinline__ float bf2f(u16 u) {
    union { unsigned int i; float f; } v; v.i = ((unsigned int)u) << 16; return v.f;
}
__device__ __forceinline__ u16 f2bf(float f) {
    union { float f; unsigned int i; } v; v.f = f;
    unsigned int x = v.i;
    return (u16)((x + 0x7FFFu + ((x >> 16) & 1u)) >> 16);   // RNE
}

// fp32 scratch carved out of the dead xp-column half of xz (rows x 8192 u16;
// cols 0..4095 dead after conv). h_loc: rows 0..1023, h_in: rows 1024..2047.
__device__ __forceinline__ float* hloc_ptr(u16* xzbase, int i) {
    return reinterpret_cast<float*>(xzbase + (size_t)(i >> 11) * 8192) + (i & 2047);
}
__device__ __forceinline__ float* hin_ptr(u16* xzbase, int i) {
    return reinterpret_cast<float*>(xzbase + (size_t)((i >> 11) + 1024) * 8192) + (i & 2047);
}

// ---------------- dtype detection -------------------------------------------
__global__ void detect_dtype(const u16* __restrict__ xraw, int* __restrict__ flag) {
    __shared__ int cnt[256];
    const int tid = threadIdx.x;
    int plausible = 0;
    for (int i = tid; i < 4096; i += 256) {
        const u16 v = xraw[2 * i];
        const int e = (v >> 7) & 0xFF;
        plausible += (e >= 100 && e <= 145) ? 1 : 0;
    }
    cnt[tid] = plausible;
    __syncthreads();
    for (int s = 128; s > 0; s >>= 1) {
        if (tid < s) cnt[tid] += cnt[tid + s];
        __syncthreads();
    }
    if (tid == 0) *flag = (cnt[0] > 2458) ? 1 : 0;
}

// ---------------- canonicalize to bf16 --------------------------------------
__global__ void cvt_bf16(const void* __restrict__ src, u16* __restrict__ dst,
                         int n, const int* __restrict__ flag) {
    const int i = blockIdx.x * 256 + threadIdx.x;
    if (i >= n) return;
    if (*flag) dst[i] = ((const u16*)src)[i];
    else       dst[i] = f2bf(((const float*)src)[i]);
}

// ---------------- flag-aware transpose (32x32 tiles, dims %32==0) -----------
__global__ void transpose_any(const void* __restrict__ in, u16* __restrict__ out,
                              int R, int C, const int* __restrict__ flag) {
    __shared__ u16 tile[32][33];
    const int c0 = blockIdx.x * 32, r0 = blockIdx.y * 32;
    const int tx = threadIdx.x, ty = threadIdx.y;   // blockDim = (32, 8)
    const bool isbf = (*flag != 0);
#pragma unroll
    for (int i = 0; i < 4; i++) {
        const size_t idx = (size_t)(r0 + ty + i * 8) * C + c0 + tx;
        tile[ty + i * 8][tx] = isbf ? ((const u16*)in)[idx]
                                    : f2bf(((const float*)in)[idx]);
    }
    __syncthreads();
#pragma unroll
    for (int i = 0; i < 4; i++)
        out[(size_t)(c0 + ty + i * 8) * R + r0 + tx] = tile[tx][ty + i * 8];
}

// ---------------- generic bf16 MFMA GEMM:  C[M,N] = A[M,K] * Bt[N,K]^T -------
// Staging: global_load_lds width=16, lane-ordered LDS (row stride 32 u16 = 64B,
// NO padding -- HW writes lane i at uniform_base + i*16).
// MODE 0: bf16 store. MODE 1: flag-aware store (bf16/fp32) for d_out.
// MODE 2: fp32 softplus(acc + bias[col]). MODE 4: fp32 atomicAdd.
template <int BM, int BN, int BK, int WR, int WC, int MT, int NT, int MODE>
__global__ __launch_bounds__(256) void gemm_bt(
    const u16* __restrict__ A, const u16* __restrict__ Bt,
    void* __restrict__ C, const u16* __restrict__ bias,
    const int* __restrict__ oflagp,
    int M, int N, int K)
{
    static_assert(BK == 32, "BK=32 (one 16x16x32 MFMA k-slab)");
    __shared__ u16 As[BM * BK];
    __shared__ u16 Bs[BN * BK];

    const int tid  = threadIdx.x;
    const int lane = tid & 63;
    const int wave = tid >> 6;
    const int wm = wave / WC, wn = wave % WC;

    const int m0 = blockIdx.y * BM;
    const int n0 = blockIdx.x * BN;
    const int Kchunk = K / gridDim.z;
    const int kbeg = blockIdx.z * Kchunk;
    const int kend = kbeg + Kchunk;

    int oflag = 1;
    if constexpr (MODE == 1) oflag = *oflagp;

    f32x4 acc[MT][NT];
#pragma unroll
    for (int mi = 0; mi < MT; mi++)
#pragma unroll
        for (int ni = 0; ni < NT; ni++)
            acc[mi][ni] = (f32x4){0.f, 0.f, 0.f, 0.f};

    const int koff = (lane >> 4) * 8;
    const int arow = wm * MT * 16 + (lane & 15);
    const int brow = wn * NT * 16 + (lane & 15);

    constexpr int CHA = BM * 4;            // 16B chunks in A tile
    constexpr int CHB = BN * 4;

    for (int k0 = kbeg; k0 < kend; k0 += BK) {
        __syncthreads();
        // async stage A tile: chunk c -> LDS byte offset c*16 (lane-ordered)
#pragma unroll
        for (int it = 0; it < (CHA + 255) / 256; it++) {
            const int c = it * 256 + tid;          // wave-uniform validity (CHA%64==0)
            if (CHA % 256 == 0 || c < CHA) {
                const int row = c >> 2, kc = c & 3;
                const u16* gp = &A[(size_t)(m0 + row) * K + k0 + kc * 8];
                __builtin_amdgcn_global_load_lds(
                    (const __attribute__((address_space(1))) void*)gp,
                    (__attribute__((address_space(3))) void*)&As[c * 8], 16, 0, 0);
            }
        }
#pragma unroll
        for (int it = 0; it < (CHB + 255) / 256; it++) {
            const int c = it * 256 + tid;
            if (CHB % 256 == 0 || c < CHB) {
                const int row = c >> 2, kc = c & 3;
                const u16* gp = &Bt[(size_t)(n0 + row) * K + k0 + kc * 8];
                __builtin_amdgcn_global_load_lds(
                    (const __attribute__((address_space(1))) void*)gp,
                    (__attribute__((address_space(3))) void*)&Bs[c * 8], 16, 0, 0);
            }
        }
        __syncthreads();   // drains vmcnt -> LDS visible

        bf16x8 af[MT], bfr[NT];
#pragma unroll
        for (int mi = 0; mi < MT; mi++)
            af[mi] = *reinterpret_cast<const bf16x8*>(&As[(arow + mi * 16) * BK + koff]);
#pragma unroll
        for (int ni = 0; ni < NT; ni++)
            bfr[ni] = *reinterpret_cast<const bf16x8*>(&Bs[(brow + ni * 16) * BK + koff]);
#pragma unroll
        for (int mi = 0; mi < MT; mi++)
#pragma unroll
            for (int ni = 0; ni < NT; ni++)
                acc[mi][ni] = __builtin_amdgcn_mfma_f32_16x16x32_bf16(
                    af[mi], bfr[ni], acc[mi][ni], 0, 0, 0);
    }

    // epilogue: D[row=(lane>>4)*4+r][col=lane&15]  (m89-verified layout)
    const int rb = m0 + wm * MT * 16 + ((lane >> 4) << 2);
    const int cb = n0 + wn * NT * 16 + (lane & 15);
#pragma unroll
    for (int mi = 0; mi < MT; mi++) {
#pragma unroll
        for (int ni = 0; ni < NT; ni++) {
            const int col = cb + ni * 16;
#pragma unroll
            for (int r = 0; r < 4; r++) {
                const int row = rb + mi * 16 + r;
                const float v = acc[mi][ni][r];
                if constexpr (MODE == 0) {
                    ((u16*)C)[(size_t)row * N + col] = f2bf(v);
                } else if constexpr (MODE == 1) {
                    if (oflag) ((u16*)C)[(size_t)row * N + col] = f2bf(v);
                    else       ((float*)C)[(size_t)row * N + col] = v;
                } else if constexpr (MODE == 2) {
                    const float x = v + bf2f(bias[col]);
                    const float sp = (x > 20.f) ? x : log1pf(__expf(x));
                    ((float*)C)[(size_t)row * N + col] = sp;
                } else if constexpr (MODE == 4) {
                    atomicAdd(((float*)C) + (size_t)row * N + col, v);
                }
            }
        }
    }
}

// ---------------- depthwise conv3 + bias + silu -----------------------------
__global__ void conv_silu(const u16* __restrict__ xz, const u16* __restrict__ conv_w,
                          const u16* __restrict__ conv_b, u16* __restrict__ xc) {
    const int idx = blockIdx.x * 256 + threadIdx.x;    // 2048*4096
    const int row = idx >> 12, c = idx & 4095;
    const int l = row & 1023;
    const float w0 = bf2f(conv_w[c * 3 + 0]);
    const float w1 = bf2f(conv_w[c * 3 + 1]);
    const float w2 = bf2f(conv_w[c * 3 + 2]);
    const float x0 = bf2f(xz[(size_t)row * 8192 + c]);
    const float xm = (l > 0)    ? bf2f(xz[(size_t)(row - 1) * 8192 + c]) : 0.f;
    const float xp = (l < 1023) ? bf2f(xz[(size_t)(row + 1) * 8192 + c]) : 0.f;
    float v = w0 * xm + w1 * x0 + w2 * xp + bf2f(conv_b[c]);
    v = v / (1.f + __expf(-v));
    xc[(size_t)row * 4096 + c] = f2bf(v);
}

// ---------------- x_dbl[:, :128] -> bf16 ------------------------------------
__global__ void cvt_dtin(const float* __restrict__ x_dbl, u16* __restrict__ dtin) {
    const int idx = blockIdx.x * 256 + threadIdx.x;    // 2048*128
    const int row = idx >> 7, c = idx & 127;
    dtin[idx] = f2bf(x_dbl[(size_t)row * 160 + c]);
}

// ---------------- S1: per-chunk local scan (h_in = 0) -----------------------
__global__ __launch_bounds__(256) void scan_p1(
    const float* __restrict__ dt, const u16* __restrict__ xc,
    const float* __restrict__ x_dbl, const u16* __restrict__ A_log,
    float* __restrict__ Parr, u16* __restrict__ xzbase)
{
    const int tid = threadIdx.x;
    const int lane = tid & 63, wave = tid >> 6;
    const int nc = blockIdx.x, cg = blockIdx.y, b = blockIdx.z;
    const int c_local = lane & 3, s = lane >> 2;
    const int ch = cg * 16 + wave * 4 + c_local;

    const float A_s = -__expf(bf2f(A_log[ch * 16 + s]));
    float h = 0.f, P = 1.f;
    const size_t row0 = (size_t)b * 1024 + nc * CLEN;

    float dt_v = dt[row0 * 4096 + ch];
    float u_v  = bf2f(xc[row0 * 4096 + ch]);
    float Bv   = x_dbl[row0 * 160 + 128 + s];

    for (int t = 0; t < CLEN; t++) {
        const int tn = (t + 1 < CLEN) ? t + 1 : t;
        const size_t rn = row0 + tn;
        const float dt_n = dt[rn * 4096 + ch];
        const float u_n  = bf2f(xc[rn * 4096 + ch]);
        const float B_n  = x_dbl[rn * 160 + 128 + s];
        const float dA = __expf(dt_v * A_s);
        P *= dA;
        h = dA * h + dt_v * Bv * u_v;
        dt_v = dt_n; u_v = u_n; Bv = B_n;
    }
    const int i = (((b * NCHUNK + nc) * 4096) + ch) * 16 + s;
    Parr[i] = P;
    *hloc_ptr(xzbase, i) = h;
}

// ---------------- S2: combine chunk summaries -> h_in -----------------------
__global__ __launch_bounds__(256) void scan_p2(
    const float* __restrict__ Parr, u16* __restrict__ xzbase)
{
    const int tid = threadIdx.x;
    const int lane = tid & 63, wave = tid >> 6;
    const int blk = blockIdx.x;
    const int b = blk >> 8, cg = blk & 255;
    const int c_local = lane & 3, s = lane >> 2;
    const int ch = cg * 16 + wave * 4 + c_local;

    float Pv[NCHUNK], hl[NCHUNK];
#pragma unroll
    for (int c = 0; c < NCHUNK; c++) {
        const int i = (((b * NCHUNK + c) * 4096) + ch) * 16 + s;
        Pv[c] = Parr[i];
        hl[c] = *hloc_ptr(xzbase, i);
    }
    float hin = 0.f;
#pragma unroll
    for (int c = 0; c < NCHUNK; c++) {
        const int i = (((b * NCHUNK + c) * 4096) + ch) * 16 + s;
        *hin_ptr(xzbase, i) = hin;
        hin = Pv[c] * hin + hl[c];
    }
}

// ---------------- S3: rescan with h_in; emit gated y ------------------------
__global__ __launch_bounds__(256) void scan_p3(
    const float* __restrict__ dt, const u16* __restrict__ xc,
    const float* __restrict__ x_dbl, const u16* __restrict__ xz,
    const u16* __restrict__ A_log, const u16* __restrict__ Dp,
    u16* __restrict__ yg, u16* __restrict__ xzbase)
{
    const int tid = threadIdx.x;
    const int lane = tid & 63, wave = tid >> 6;
    const int nc = blockIdx.x, cg = blockIdx.y, b = blockIdx.z;
    const int c_local = lane & 3, s = lane >> 2;
    const int ch = cg * 16 + wave * 4 + c_local;

    const float A_s = -__expf(bf2f(A_log[ch * 16 + s]));
    const float D_ch = bf2f(Dp[ch]);
    const int i0 = (((b * NCHUNK + nc) * 4096) + ch) * 16 + s;
    float h = *hin_ptr(xzbase, i0);
    float ybuf = 0.f;
    const size_t row0 = (size_t)b * 1024 + nc * CLEN;

    float dt_v = dt[row0 * 4096 + ch];
    float u_v  = bf2f(xc[row0 * 4096 + ch]);
    float Bv   = x_dbl[row0 * 160 + 128 + s];
    float Cv   = x_dbl[row0 * 160 + 144 + s];
    float z_v  = bf2f(xz[row0 * 8192 + 4096 + ch]);

    for (int t = 0; t < CLEN; t++) {
        const int tn = (t + 1 < CLEN) ? t + 1 : t;
        const size_t rn = row0 + tn;
        const float dt_n = dt[rn * 4096 + ch];
        const float u_n  = bf2f(xc[rn * 4096 + ch]);
        const float B_n  = x_dbl[rn * 160 + 128 + s];
        const float C_n  = x_dbl[rn * 160 + 144 + s];
        const float z_n  = bf2f(xz[rn * 8192 + 4096 + ch]);

        const float dA = __expf(dt_v * A_s);
        h = dA * h + dt_v * Bv * u_v;
        float p = h * Cv;
        p += __shfl_xor(p, 4);
        p += __shfl_xor(p, 8);
        p += __shfl_xor(p, 16);
        p += __shfl_xor(p, 32);
        const float silu_z = z_v / (1.f + __expf(-z_v));
        const float yv = (p + u_v * D_ch) * silu_z;
        ybuf = (s == (t & 15)) ? yv : ybuf;
        if ((t & 15) == 15) {
            const size_t orow = row0 + (size_t)(t - 15 + s);
            yg[orow * 4096 + ch] = f2bf(ybuf);
        }
        dt_v = dt_n; u_v = u_n; Bv = B_n; Cv = C_n; z_v = z_n;
    }
}

extern "C" void kernel_launch(void* const* d_in, const int* in_sizes, int n_in,
                              void* d_out, int out_size, void* d_ws, size_t ws_size,
                              hipStream_t stream)
{
    const void* x_raw      = d_in[0];   // (2,1024,2048)
    const void* W_in_raw   = d_in[1];   // (2048,8192)
    const void* conv_w_raw = d_in[2];   // (4096,1,3)
    const void* conv_b_raw = d_in[3];   // (4096)
    const void* W_x_raw    = d_in[4];   // (4096,160)
    const void* W_dt_raw   = d_in[5];   // (128,4096)
    const void* b_dt_raw   = d_in[6];   // (4096)
    const void* A_log_raw  = d_in[7];   // (4096,16)
    const void* D_raw      = d_in[8];   // (4096)
    const void* W_out_raw  = d_in[9];   // (4096,2048)

    char* ws = (char*)d_ws;
    size_t off = 0;
    auto alloc = [&](size_t bytes) { char* p = ws + off; off += (bytes + 255) & ~(size_t)255; return p; };
    int*   flag   = (int*)  alloc(4);
    u16*   W_inT  = (u16*)  alloc(8192ULL * 2048 * 2);   // 32 MB (aliased by dt fp32 after K1)
    u16*   W_outT = (u16*)  alloc(2048ULL * 4096 * 2);   // 16 MB
    u16*   W_dtT  = (u16*)  alloc(4096ULL * 128 * 2);    // 1 MB
    u16*   W_xT   = (u16*)  alloc(160ULL * 4096 * 2);    // 1.25 MB
    u16*   xz     = (u16*)  alloc(2048ULL * 8192 * 2);   // 32 MB (xp half reused as h_loc/h_in)
    u16*   xc     = (u16*)  alloc(2048ULL * 4096 * 2);   // 16 MB
    float* x_dbl  = (float*)alloc(2048ULL * 160 * 4);    // 1.25 MB
    u16*   dtin   = (u16*)  alloc(2048ULL * 128 * 2);    // 0.5 MB
    u16*   yg     = (u16*)  alloc(2048ULL * 4096 * 2);   // 16 MB
    u16*   xcan   = (u16*)  alloc(2048ULL * 2048 * 2);   // 8 MB (reused as Parr fp32)
    u16*   cw_c   = (u16*)  alloc(12288 * 2);
    u16*   cb_c   = (u16*)  alloc(4096 * 2);
    u16*   bdt_c  = (u16*)  alloc(4096 * 2);
    u16*   Alog_c = (u16*)  alloc(65536 * 2);
    u16*   D_c    = (u16*)  alloc(4096 * 2);
    float* dtv    = (float*)W_inT;   // alias: W_inT dead after K1 (32 MB exact)
    float* Parr   = (float*)xcan;    // alias: xcan dead after K1 (8 MB exact)

    // D) dtype flag + canonicalize
    detect_dtype<<<1, 256, 0, stream>>>((const u16*)x_raw, flag);
    cvt_bf16<<<(2048 * 2048) / 256, 256, 0, stream>>>(x_raw, xcan, 2048 * 2048, flag);
    cvt_bf16<<<48, 256, 0, stream>>>(conv_w_raw, cw_c, 12288, flag);
    cvt_bf16<<<16, 256, 0, stream>>>(conv_b_raw, cb_c, 4096, flag);
    cvt_bf16<<<16, 256, 0, stream>>>(b_dt_raw, bdt_c, 4096, flag);
    cvt_bf16<<<256, 256, 0, stream>>>(A_log_raw, Alog_c, 65536, flag);
    cvt_bf16<<<16, 256, 0, stream>>>(D_raw, D_c, 4096, flag);

    // T) transposes
    const dim3 tb(32, 8);
    transpose_any<<<dim3(8192 / 32, 2048 / 32), tb, 0, stream>>>(W_in_raw,  W_inT,  2048, 8192, flag);
    transpose_any<<<dim3(2048 / 32, 4096 / 32), tb, 0, stream>>>(W_out_raw, W_outT, 4096, 2048, flag);
    transpose_any<<<dim3(4096 / 32, 128 / 32),  tb, 0, stream>>>(W_dt_raw,  W_dtT,  128,  4096, flag);
    transpose_any<<<dim3(160 / 32, 4096 / 32),  tb, 0, stream>>>(W_x_raw,   W_xT,   4096, 160,  flag);

    // K1: xz = x @ W_in   (M=2048, N=8192, K=2048)
    gemm_bt<128, 128, 32, 2, 2, 4, 4, 0>
        <<<dim3(8192 / 128, 2048 / 128, 1), 256, 0, stream>>>(xcan, W_inT, xz, nullptr, nullptr, 2048, 8192, 2048);

    // K2: conv + bias + silu
    conv_silu<<<(2048 * 4096) / 256, 256, 0, stream>>>(xz, cw_c, cb_c, xc);

    // K3: x_dbl = xc @ W_x   (split-K=8, atomic fp32)
    hipMemsetAsync(x_dbl, 0, 2048ULL * 160 * 4, stream);
    gemm_bt<64, 160, 32, 4, 1, 1, 10, 4>
        <<<dim3(1, 2048 / 64, 8), 256, 0, stream>>>(xc, W_xT, x_dbl, nullptr, nullptr, 2048, 160, 4096);

    cvt_dtin<<<(2048 * 128) / 256, 256, 0, stream>>>(x_dbl, dtin);

    // K4: dt = softplus(dtin @ W_dt + b_dt)   (fp32 out)
    gemm_bt<128, 128, 32, 2, 2, 4, 4, 2>
        <<<dim3(4096 / 128, 2048 / 128, 1), 256, 0, stream>>>(dtin, W_dtT, dtv, bdt_c, nullptr, 2048, 4096, 128);

    // S1/S2/S3: chunked selective scan + gating
    scan_p1<<<dim3(NCHUNK, 256, 2), 256, 0, stream>>>(dtv, xc, x_dbl, Alog_c, Parr, xz);
    scan_p2<<<512, 256, 0, stream>>>(Parr, xz);
    scan_p3<<<dim3(NCHUNK, 256, 2), 256, 0, stream>>>(dtv, xc, x_dbl, xz, Alog_c, D_c, yg, xz);

    // K6: out = yg @ W_out   (M=2048, N=2048, K=4096), flag-aware store
    gemm_bt<128, 128, 32, 2, 2, 4, 4, 1>
        <<<dim3(2048 / 128, 2048 / 128, 1), 256, 0, stream>>>(yg, W_outT, d_out, nullptr, flag, 2048, 2048, 4096);
}

// Round 5
// 645.861 us; speedup vs baseline: 1.6403x; 1.1148x over previous
//
#include <hip/hip_runtime.h>
#include <hip/hip_bf16.h>

// Selective SSM (Mamba-style): B=2, L=1024, H=2048, E=2 -> d=4096, S=16, R=128.
// Round 5: (a) split gating out of scan_p3 into a memory-bound gate_kernel
// (removes silu/D/gate VALU redundancy from the 91%-VALU-busy scan);
// (b) fuse 6 cvt kernels + memset into one, 4 transposes into one
// (19 -> 13 dispatches; ~10us launch gap each).

using u16 = unsigned short;
typedef __bf16 bf16x8 __attribute__((ext_vector_type(8)));
typedef float f32x4 __attribute__((ext_vector_type(4)));

#define NCHUNK 16
#define CLEN   64

__device__ __forceinline__ float bf2f(u16 u) {
    union { unsigned int i; float f; } v; v.i = ((unsigned int)u) << 16; return v.f;
}
__device__ __forceinline__ u16 f2bf(float f) {
    union { float f; unsigned int i; } v; v.f = f;
    unsigned int x = v.i;
    return (u16)((x + 0x7FFFu + ((x >> 16) & 1u)) >> 16);   // RNE
}

// fp32 scratch carved out of the dead xp-column half of xz (rows x 8192 u16;
// cols 0..4095 dead after conv). h_loc: rows 0..1023, h_in: rows 1024..2047.
__device__ __forceinline__ float* hloc_ptr(u16* xzbase, int i) {
    return reinterpret_cast<float*>(xzbase + (size_t)(i >> 11) * 8192) + (i & 2047);
}
__device__ __forceinline__ float* hin_ptr(u16* xzbase, int i) {
    return reinterpret_cast<float*>(xzbase + (size_t)((i >> 11) + 1024) * 8192) + (i & 2047);
}

// ---------------- dtype detection -------------------------------------------
__global__ void detect_dtype(const u16* __restrict__ xraw, int* __restrict__ flag) {
    __shared__ int cnt[256];
    const int tid = threadIdx.x;
    int plausible = 0;
    for (int i = tid; i < 4096; i += 256) {
        const u16 v = xraw[2 * i];
        const int e = (v >> 7) & 0xFF;
        plausible += (e >= 100 && e <= 145) ? 1 : 0;
    }
    cnt[tid] = plausible;
    __syncthreads();
    for (int s = 128; s > 0; s >>= 1) {
        if (tid < s) cnt[tid] += cnt[tid + s];
        __syncthreads();
    }
    if (tid == 0) *flag = (cnt[0] > 2458) ? 1 : 0;
}

// ---------------- fused canonicalize (6 tensors) + x_dbl zero ---------------
__device__ __forceinline__ void cvt_seg(const void* src, u16* dst, int i,
                                        bool isbf) {
    dst[i] = isbf ? ((const u16*)src)[i] : f2bf(((const float*)src)[i]);
}
__global__ void cvt_fused(const void* __restrict__ x_raw, u16* __restrict__ xcan,
                          const void* __restrict__ cw_raw, u16* __restrict__ cw_c,
                          const void* __restrict__ cb_raw, u16* __restrict__ cb_c,
                          const void* __restrict__ bdt_raw, u16* __restrict__ bdt_c,
                          const void* __restrict__ Alog_raw, u16* __restrict__ Alog_c,
                          const void* __restrict__ D_raw, u16* __restrict__ D_c,
                          float* __restrict__ x_dbl,
                          const int* __restrict__ flag) {
    const bool isbf = (*flag != 0);
    int blk = blockIdx.x;
    const int tid = threadIdx.x;
    if (blk < 16384) { cvt_seg(x_raw, xcan, blk * 256 + tid, isbf); return; }
    blk -= 16384;
    if (blk < 48)  { cvt_seg(cw_raw, cw_c, blk * 256 + tid, isbf); return; }
    blk -= 48;
    if (blk < 16)  { cvt_seg(cb_raw, cb_c, blk * 256 + tid, isbf); return; }
    blk -= 16;
    if (blk < 16)  { cvt_seg(bdt_raw, bdt_c, blk * 256 + tid, isbf); return; }
    blk -= 16;
    if (blk < 256) { cvt_seg(Alog_raw, Alog_c, blk * 256 + tid, isbf); return; }
    blk -= 256;
    if (blk < 16)  { cvt_seg(D_raw, D_c, blk * 256 + tid, isbf); return; }
    blk -= 16;
    x_dbl[blk * 256 + tid] = 0.f;       // 1280 blocks: zero 2048*160 fp32
}

// ---------------- fused flag-aware transposes (4 tensors) -------------------
__device__ __forceinline__ void tr_tile(const void* in, u16* out, int R, int C,
                                        int bx, int by, int tx, int ty, bool isbf,
                                        u16 (*tile)[33]) {
    const int c0 = bx * 32, r0 = by * 32;
#pragma unroll
    for (int i = 0; i < 4; i++) {
        const size_t idx = (size_t)(r0 + ty + i * 8) * C + c0 + tx;
        tile[ty + i * 8][tx] = isbf ? ((const u16*)in)[idx]
                                    : f2bf(((const float*)in)[idx]);
    }
    __syncthreads();
#pragma unroll
    for (int i = 0; i < 4; i++)
        out[(size_t)(c0 + ty + i * 8) * R + r0 + tx] = tile[tx][ty + i * 8];
}
__global__ void transpose_fused(const void* __restrict__ Wi, u16* __restrict__ WiT,
                                const void* __restrict__ Wo, u16* __restrict__ WoT,
                                const void* __restrict__ Wd, u16* __restrict__ WdT,
                                const void* __restrict__ Wx, u16* __restrict__ WxT,
                                const int* __restrict__ flag) {
    __shared__ u16 tile[32][33];
    const bool isbf = (*flag != 0);
    const int tx = threadIdx.x, ty = threadIdx.y;   // (32,8)
    int blk = blockIdx.x;
    if (blk < 16384) { tr_tile(Wi, WiT, 2048, 8192, blk % 256, blk / 256, tx, ty, isbf, tile); return; }
    blk -= 16384;
    if (blk < 8192)  { tr_tile(Wo, WoT, 4096, 2048, blk % 64, blk / 64, tx, ty, isbf, tile); return; }
    blk -= 8192;
    if (blk < 512)   { tr_tile(Wd, WdT, 128, 4096, blk % 128, blk / 128, tx, ty, isbf, tile); return; }
    blk -= 512;
    tr_tile(Wx, WxT, 4096, 160, blk % 5, blk / 5, tx, ty, isbf, tile);   // 640 blocks
}

// ---------------- generic bf16 MFMA GEMM:  C[M,N] = A[M,K] * Bt[N,K]^T -------
// Staging: global_load_lds width=16, lane-ordered LDS (no padding).
// MODE 0: bf16 store. MODE 1: flag-aware store (bf16/fp32) for d_out.
// MODE 2: fp32 softplus(acc + bias[col]). MODE 4: fp32 atomicAdd.
template <int BM, int BN, int BK, int WR, int WC, int MT, int NT, int MODE>
__global__ __launch_bounds__(256) void gemm_bt(
    const u16* __restrict__ A, const u16* __restrict__ Bt,
    void* __restrict__ C, const u16* __restrict__ bias,
    const int* __restrict__ oflagp,
    int M, int N, int K)
{
    static_assert(BK == 32, "BK=32 (one 16x16x32 MFMA k-slab)");
    __shared__ u16 As[BM * BK];
    __shared__ u16 Bs[BN * BK];

    const int tid  = threadIdx.x;
    const int lane = tid & 63;
    const int wave = tid >> 6;
    const int wm = wave / WC, wn = wave % WC;

    const int m0 = blockIdx.y * BM;
    const int n0 = blockIdx.x * BN;
    const int Kchunk = K / gridDim.z;
    const int kbeg = blockIdx.z * Kchunk;
    const int kend = kbeg + Kchunk;

    int oflag = 1;
    if constexpr (MODE == 1) oflag = *oflagp;

    f32x4 acc[MT][NT];
#pragma unroll
    for (int mi = 0; mi < MT; mi++)
#pragma unroll
        for (int ni = 0; ni < NT; ni++)
            acc[mi][ni] = (f32x4){0.f, 0.f, 0.f, 0.f};

    const int koff = (lane >> 4) * 8;
    const int arow = wm * MT * 16 + (lane & 15);
    const int brow = wn * NT * 16 + (lane & 15);

    constexpr int CHA = BM * 4;            // 16B chunks in A tile
    constexpr int CHB = BN * 4;

    for (int k0 = kbeg; k0 < kend; k0 += BK) {
        __syncthreads();
#pragma unroll
        for (int it = 0; it < (CHA + 255) / 256; it++) {
            const int c = it * 256 + tid;
            if (CHA % 256 == 0 || c < CHA) {
                const int row = c >> 2, kc = c & 3;
                const u16* gp = &A[(size_t)(m0 + row) * K + k0 + kc * 8];
                __builtin_amdgcn_global_load_lds(
                    (const __attribute__((address_space(1))) void*)gp,
                    (__attribute__((address_space(3))) void*)&As[c * 8], 16, 0, 0);
            }
        }
#pragma unroll
        for (int it = 0; it < (CHB + 255) / 256; it++) {
            const int c = it * 256 + tid;
            if (CHB % 256 == 0 || c < CHB) {
                const int row = c >> 2, kc = c & 3;
                const u16* gp = &Bt[(size_t)(n0 + row) * K + k0 + kc * 8];
                __builtin_amdgcn_global_load_lds(
                    (const __attribute__((address_space(1))) void*)gp,
                    (__attribute__((address_space(3))) void*)&Bs[c * 8], 16, 0, 0);
            }
        }
        __syncthreads();

        bf16x8 af[MT], bfr[NT];
#pragma unroll
        for (int mi = 0; mi < MT; mi++)
            af[mi] = *reinterpret_cast<const bf16x8*>(&As[(arow + mi * 16) * BK + koff]);
#pragma unroll
        for (int ni = 0; ni < NT; ni++)
            bfr[ni] = *reinterpret_cast<const bf16x8*>(&Bs[(brow + ni * 16) * BK + koff]);
#pragma unroll
        for (int mi = 0; mi < MT; mi++)
#pragma unroll
            for (int ni = 0; ni < NT; ni++)
                acc[mi][ni] = __builtin_amdgcn_mfma_f32_16x16x32_bf16(
                    af[mi], bfr[ni], acc[mi][ni], 0, 0, 0);
    }

    const int rb = m0 + wm * MT * 16 + ((lane >> 4) << 2);
    const int cb = n0 + wn * NT * 16 + (lane & 15);
#pragma unroll
    for (int mi = 0; mi < MT; mi++) {
#pragma unroll
        for (int ni = 0; ni < NT; ni++) {
            const int col = cb + ni * 16;
#pragma unroll
            for (int r = 0; r < 4; r++) {
                const int row = rb + mi * 16 + r;
                const float v = acc[mi][ni][r];
                if constexpr (MODE == 0) {
                    ((u16*)C)[(size_t)row * N + col] = f2bf(v);
                } else if constexpr (MODE == 1) {
                    if (oflag) ((u16*)C)[(size_t)row * N + col] = f2bf(v);
                    else       ((float*)C)[(size_t)row * N + col] = v;
                } else if constexpr (MODE == 2) {
                    const float x = v + bf2f(bias[col]);
                    const float sp = (x > 20.f) ? x : log1pf(__expf(x));
                    ((float*)C)[(size_t)row * N + col] = sp;
                } else if constexpr (MODE == 4) {
                    atomicAdd(((float*)C) + (size_t)row * N + col, v);
                }
            }
        }
    }
}

// ---------------- depthwise conv3 + bias + silu -----------------------------
__global__ void conv_silu(const u16* __restrict__ xz, const u16* __restrict__ conv_w,
                          const u16* __restrict__ conv_b, u16* __restrict__ xc) {
    const int idx = blockIdx.x * 256 + threadIdx.x;    // 2048*4096
    const int row = idx >> 12, c = idx & 4095;
    const int l = row & 1023;
    const float w0 = bf2f(conv_w[c * 3 + 0]);
    const float w1 = bf2f(conv_w[c * 3 + 1]);
    const float w2 = bf2f(conv_w[c * 3 + 2]);
    const float x0 = bf2f(xz[(size_t)row * 8192 + c]);
    const float xm = (l > 0)    ? bf2f(xz[(size_t)(row - 1) * 8192 + c]) : 0.f;
    const float xp = (l < 1023) ? bf2f(xz[(size_t)(row + 1) * 8192 + c]) : 0.f;
    float v = w0 * xm + w1 * x0 + w2 * xp + bf2f(conv_b[c]);
    v = v / (1.f + __expf(-v));
    xc[(size_t)row * 4096 + c] = f2bf(v);
}

// ---------------- x_dbl[:, :128] -> bf16 ------------------------------------
__global__ void cvt_dtin(const float* __restrict__ x_dbl, u16* __restrict__ dtin) {
    const int idx = blockIdx.x * 256 + threadIdx.x;    // 2048*128
    const int row = idx >> 7, c = idx & 127;
    dtin[idx] = f2bf(x_dbl[(size_t)row * 160 + c]);
}

// ---------------- S1: per-chunk local scan (h_in = 0) -----------------------
__global__ __launch_bounds__(256) void scan_p1(
    const float* __restrict__ dt, const u16* __restrict__ xc,
    const float* __restrict__ x_dbl, const u16* __restrict__ A_log,
    float* __restrict__ Parr, u16* __restrict__ xzbase)
{
    const int tid = threadIdx.x;
    const int lane = tid & 63, wave = tid >> 6;
    const int nc = blockIdx.x, cg = blockIdx.y, b = blockIdx.z;
    const int c_local = lane & 3, s = lane >> 2;
    const int ch = cg * 16 + wave * 4 + c_local;

    const float A_s = -__expf(bf2f(A_log[ch * 16 + s]));
    float h = 0.f, P = 1.f;
    const size_t row0 = (size_t)b * 1024 + nc * CLEN;

    float dt_v = dt[row0 * 4096 + ch];
    float u_v  = bf2f(xc[row0 * 4096 + ch]);
    float Bv   = x_dbl[row0 * 160 + 128 + s];

    for (int t = 0; t < CLEN; t++) {
        const int tn = (t + 1 < CLEN) ? t + 1 : t;
        const size_t rn = row0 + tn;
        const float dt_n = dt[rn * 4096 + ch];
        const float u_n  = bf2f(xc[rn * 4096 + ch]);
        const float B_n  = x_dbl[rn * 160 + 128 + s];
        const float dA = __expf(dt_v * A_s);
        P *= dA;
        h = dA * h + dt_v * Bv * u_v;
        dt_v = dt_n; u_v = u_n; Bv = B_n;
    }
    const int i = (((b * NCHUNK + nc) * 4096) + ch) * 16 + s;
    Parr[i] = P;
    *hloc_ptr(xzbase, i) = h;
}

// ---------------- S2: combine chunk summaries -> h_in -----------------------
__global__ __launch_bounds__(256) void scan_p2(
    const float* __restrict__ Parr, u16* __restrict__ xzbase)
{
    const int tid = threadIdx.x;
    const int lane = tid & 63, wave = tid >> 6;
    const int blk = blockIdx.x;
    const int b = blk >> 8, cg = blk & 255;
    const int c_local = lane & 3, s = lane >> 2;
    const int ch = cg * 16 + wave * 4 + c_local;

    float Pv[NCHUNK], hl[NCHUNK];
#pragma unroll
    for (int c = 0; c < NCHUNK; c++) {
        const int i = (((b * NCHUNK + c) * 4096) + ch) * 16 + s;
        Pv[c] = Parr[i];
        hl[c] = *hloc_ptr(xzbase, i);
    }
    float hin = 0.f;
#pragma unroll
    for (int c = 0; c < NCHUNK; c++) {
        const int i = (((b * NCHUNK + c) * 4096) + ch) * 16 + s;
        *hin_ptr(xzbase, i) = hin;
        hin = Pv[c] * hin + hl[c];
    }
}

// ---------------- S3: rescan with h_in; emit raw p = C.h (bf16) -------------
__global__ __launch_bounds__(256) void scan_p3(
    const float* __restrict__ dt, const u16* __restrict__ xc,
    const float* __restrict__ x_dbl, const u16* __restrict__ A_log,
    u16* __restrict__ pg, u16* __restrict__ xzbase)
{
    const int tid = threadIdx.x;
    const int lane = tid & 63, wave = tid >> 6;
    const int nc = blockIdx.x, cg = blockIdx.y, b = blockIdx.z;
    const int c_local = lane & 3, s = lane >> 2;
    const int ch = cg * 16 + wave * 4 + c_local;

    const float A_s = -__expf(bf2f(A_log[ch * 16 + s]));
    const int i0 = (((b * NCHUNK + nc) * 4096) + ch) * 16 + s;
    float h = *hin_ptr(xzbase, i0);
    float ybuf = 0.f;
    const size_t row0 = (size_t)b * 1024 + nc * CLEN;

    float dt_v = dt[row0 * 4096 + ch];
    float u_v  = bf2f(xc[row0 * 4096 + ch]);
    float Bv   = x_dbl[row0 * 160 + 128 + s];
    float Cv   = x_dbl[row0 * 160 + 144 + s];

    for (int t = 0; t < CLEN; t++) {
        const int tn = (t + 1 < CLEN) ? t + 1 : t;
        const size_t rn = row0 + tn;
        const float dt_n = dt[rn * 4096 + ch];
        const float u_n  = bf2f(xc[rn * 4096 + ch]);
        const float B_n  = x_dbl[rn * 160 + 128 + s];
        const float C_n  = x_dbl[rn * 160 + 144 + s];

        const float dA = __expf(dt_v * A_s);
        h = dA * h + dt_v * Bv * u_v;
        float p = h * Cv;
        p += __shfl_xor(p, 4);
        p += __shfl_xor(p, 8);
        p += __shfl_xor(p, 16);
        p += __shfl_xor(p, 32);
        ybuf = (s == (t & 15)) ? p : ybuf;
        if ((t & 15) == 15) {
            const size_t orow = row0 + (size_t)(t - 15 + s);
            pg[orow * 4096 + ch] = f2bf(ybuf);
        }
        dt_v = dt_n; u_v = u_n; Bv = B_n; Cv = C_n;
    }
}

// ---------------- gate: yg = (p + u*D) * silu(z)  (in-place on pg) ----------
__global__ void gate_kernel(u16* __restrict__ pg, const u16* __restrict__ xc,
                            const u16* __restrict__ xz, const u16* __restrict__ Dp) {
    const int idx = blockIdx.x * 256 + threadIdx.x;    // 2048*4096
    const int row = idx >> 12, c = idx & 4095;
    const float p = bf2f(pg[idx]);
    const float u = bf2f(xc[idx]);
    const float z = bf2f(xz[(size_t)row * 8192 + 4096 + c]);
    const float silu_z = z / (1.f + __expf(-z));
    pg[idx] = f2bf((p + u * bf2f(Dp[c])) * silu_z);
}

extern "C" void kernel_launch(void* const* d_in, const int* in_sizes, int n_in,
                              void* d_out, int out_size, void* d_ws, size_t ws_size,
                              hipStream_t stream)
{
    const void* x_raw      = d_in[0];   // (2,1024,2048)
    const void* W_in_raw   = d_in[1];   // (2048,8192)
    const void* conv_w_raw = d_in[2];   // (4096,1,3)
    const void* conv_b_raw = d_in[3];   // (4096)
    const void* W_x_raw    = d_in[4];   // (4096,160)
    const void* W_dt_raw   = d_in[5];   // (128,4096)
    const void* b_dt_raw   = d_in[6];   // (4096)
    const void* A_log_raw  = d_in[7];   // (4096,16)
    const void* D_raw      = d_in[8];   // (4096)
    const void* W_out_raw  = d_in[9];   // (4096,2048)

    char* ws = (char*)d_ws;
    size_t off = 0;
    auto alloc = [&](size_t bytes) { char* p = ws + off; off += (bytes + 255) & ~(size_t)255; return p; };
    int*   flag   = (int*)  alloc(4);
    u16*   W_inT  = (u16*)  alloc(8192ULL * 2048 * 2);   // 32 MB (aliased by dt fp32 after K1)
    u16*   W_outT = (u16*)  alloc(2048ULL * 4096 * 2);   // 16 MB
    u16*   W_dtT  = (u16*)  alloc(4096ULL * 128 * 2);    // 1 MB
    u16*   W_xT   = (u16*)  alloc(160ULL * 4096 * 2);    // 1.25 MB
    u16*   xz     = (u16*)  alloc(2048ULL * 8192 * 2);   // 32 MB (xp half reused as h_loc/h_in)
    u16*   xc     = (u16*)  alloc(2048ULL * 4096 * 2);   // 16 MB
    float* x_dbl  = (float*)alloc(2048ULL * 160 * 4);    // 1.25 MB
    u16*   dtin   = (u16*)  alloc(2048ULL * 128 * 2);    // 0.5 MB
    u16*   yg     = (u16*)  alloc(2048ULL * 4096 * 2);   // 16 MB (p, then gated y)
    u16*   xcan   = (u16*)  alloc(2048ULL * 2048 * 2);   // 8 MB (reused as Parr fp32)
    u16*   cw_c   = (u16*)  alloc(12288 * 2);
    u16*   cb_c   = (u16*)  alloc(4096 * 2);
    u16*   bdt_c  = (u16*)  alloc(4096 * 2);
    u16*   Alog_c = (u16*)  alloc(65536 * 2);
    u16*   D_c    = (u16*)  alloc(4096 * 2);
    float* dtv    = (float*)W_inT;   // alias: W_inT dead after K1 (32 MB exact)
    float* Parr   = (float*)xcan;    // alias: xcan dead after K1 (8 MB exact)

    // D) dtype flag, fused canonicalize + x_dbl zero
    detect_dtype<<<1, 256, 0, stream>>>((const u16*)x_raw, flag);
    cvt_fused<<<16384 + 48 + 16 + 16 + 256 + 16 + 1280, 256, 0, stream>>>(
        x_raw, xcan, conv_w_raw, cw_c, conv_b_raw, cb_c, b_dt_raw, bdt_c,
        A_log_raw, Alog_c, D_raw, D_c, x_dbl, flag);

    // T) fused transposes
    transpose_fused<<<16384 + 8192 + 512 + 640, dim3(32, 8), 0, stream>>>(
        W_in_raw, W_inT, W_out_raw, W_outT, W_dt_raw, W_dtT, W_x_raw, W_xT, flag);

    // K1: xz = x @ W_in   (M=2048, N=8192, K=2048)
    gemm_bt<128, 128, 32, 2, 2, 4, 4, 0>
        <<<dim3(8192 / 128, 2048 / 128, 1), 256, 0, stream>>>(xcan, W_inT, xz, nullptr, nullptr, 2048, 8192, 2048);

    // K2: conv + bias + silu
    conv_silu<<<(2048 * 4096) / 256, 256, 0, stream>>>(xz, cw_c, cb_c, xc);

    // K3: x_dbl = xc @ W_x   (split-K=8, atomic fp32; x_dbl zeroed in cvt_fused)
    gemm_bt<64, 160, 32, 4, 1, 1, 10, 4>
        <<<dim3(1, 2048 / 64, 8), 256, 0, stream>>>(xc, W_xT, x_dbl, nullptr, nullptr, 2048, 160, 4096);

    cvt_dtin<<<(2048 * 128) / 256, 256, 0, stream>>>(x_dbl, dtin);

    // K4: dt = softplus(dtin @ W_dt + b_dt)   (fp32 out)
    gemm_bt<128, 128, 32, 2, 2, 4, 4, 2>
        <<<dim3(4096 / 128, 2048 / 128, 1), 256, 0, stream>>>(dtin, W_dtT, dtv, bdt_c, nullptr, 2048, 4096, 128);

    // S1/S2/S3: chunked selective scan (raw p out), then gate
    scan_p1<<<dim3(NCHUNK, 256, 2), 256, 0, stream>>>(dtv, xc, x_dbl, Alog_c, Parr, xz);
    scan_p2<<<512, 256, 0, stream>>>(Parr, xz);
    scan_p3<<<dim3(NCHUNK, 256, 2), 256, 0, stream>>>(dtv, xc, x_dbl, Alog_c, yg, xz);
    gate_kernel<<<(2048 * 4096) / 256, 256, 0, stream>>>(yg, xc, xz, D_c);

    // K6: out = yg @ W_out   (M=2048, N=2048, K=4096), flag-aware store
    gemm_bt<128, 128, 32, 2, 2, 4, 4, 1>
        <<<dim3(2048 / 128, 2048 / 128, 1), 256, 0, stream>>>(yg, W_outT, d_out, nullptr, flag, 2048, 2048, 4096);
}

// Round 7
// 549.253 us; speedup vs baseline: 1.9288x; 1.1759x over previous
//
#include <hip/hip_runtime.h>
#include <hip/hip_bf16.h>

// Selective SSM (Mamba-style): B=2, L=1024, H=2048, E=2 -> d=4096, S=16, R=128.
// Round 7 = Round 6 resubmit (container infra failure, kernel never ran).
// Scan layout transposed to lane=channel, 16 states in registers:
// no cross-lane shuffles, coalesced dt/u/z loads (once per channel, not 16x),
// B/C staged once per block in LDS (broadcast reads). P via exp(A*Sum(dt)).
// Gating fused back into scan_p3 (gate_kernel removed).

using u16 = unsigned short;
typedef __bf16 bf16x8 __attribute__((ext_vector_type(8)));
typedef float f32x4 __attribute__((ext_vector_type(4)));

#define NCHUNK 16
#define CLEN   64

__device__ __forceinline__ float bf2f(u16 u) {
    union { unsigned int i; float f; } v; v.i = ((unsigned int)u) << 16; return v.f;
}
__device__ __forceinline__ u16 f2bf(float f) {
    union { float f; unsigned int i; } v; v.f = f;
    unsigned int x = v.i;
    return (u16)((x + 0x7FFFu + ((x >> 16) & 1u)) >> 16);   // RNE
}

// fp32 scratch carved out of the dead xp-column half of xz (rows x 8192 u16;
// cols 0..4095 dead after conv). h_loc: rows 0..1023, h_in: rows 1024..2047.
__device__ __forceinline__ float* hloc_ptr(u16* xzbase, int i) {
    return reinterpret_cast<float*>(xzbase + (size_t)(i >> 11) * 8192) + (i & 2047);
}
__device__ __forceinline__ float* hin_ptr(u16* xzbase, int i) {
    return reinterpret_cast<float*>(xzbase + (size_t)((i >> 11) + 1024) * 8192) + (i & 2047);
}

// ---------------- dtype detection -------------------------------------------
__global__ void detect_dtype(const u16* __restrict__ xraw, int* __restrict__ flag) {
    __shared__ int cnt[256];
    const int tid = threadIdx.x;
    int plausible = 0;
    for (int i = tid; i < 4096; i += 256) {
        const u16 v = xraw[2 * i];
        const int e = (v >> 7) & 0xFF;
        plausible += (e >= 100 && e <= 145) ? 1 : 0;
    }
    cnt[tid] = plausible;
    __syncthreads();
    for (int s = 128; s > 0; s >>= 1) {
        if (tid < s) cnt[tid] += cnt[tid + s];
        __syncthreads();
    }
    if (tid == 0) *flag = (cnt[0] > 2458) ? 1 : 0;
}

// ---------------- fused canonicalize (6 tensors) + x_dbl zero ---------------
__device__ __forceinline__ void cvt_seg(const void* src, u16* dst, int i,
                                        bool isbf) {
    dst[i] = isbf ? ((const u16*)src)[i] : f2bf(((const float*)src)[i]);
}
__global__ void cvt_fused(const void* __restrict__ x_raw, u16* __restrict__ xcan,
                          const void* __restrict__ cw_raw, u16* __restrict__ cw_c,
                          const void* __restrict__ cb_raw, u16* __restrict__ cb_c,
                          const void* __restrict__ bdt_raw, u16* __restrict__ bdt_c,
                          const void* __restrict__ Alog_raw, u16* __restrict__ Alog_c,
                          const void* __restrict__ D_raw, u16* __restrict__ D_c,
                          float* __restrict__ x_dbl,
                          const int* __restrict__ flag) {
    const bool isbf = (*flag != 0);
    int blk = blockIdx.x;
    const int tid = threadIdx.x;
    if (blk < 16384) { cvt_seg(x_raw, xcan, blk * 256 + tid, isbf); return; }
    blk -= 16384;
    if (blk < 48)  { cvt_seg(cw_raw, cw_c, blk * 256 + tid, isbf); return; }
    blk -= 48;
    if (blk < 16)  { cvt_seg(cb_raw, cb_c, blk * 256 + tid, isbf); return; }
    blk -= 16;
    if (blk < 16)  { cvt_seg(bdt_raw, bdt_c, blk * 256 + tid, isbf); return; }
    blk -= 16;
    if (blk < 256) { cvt_seg(Alog_raw, Alog_c, blk * 256 + tid, isbf); return; }
    blk -= 256;
    if (blk < 16)  { cvt_seg(D_raw, D_c, blk * 256 + tid, isbf); return; }
    blk -= 16;
    x_dbl[blk * 256 + tid] = 0.f;       // 1280 blocks: zero 2048*160 fp32
}

// ---------------- fused flag-aware transposes (4 tensors) -------------------
__device__ __forceinline__ void tr_tile(const void* in, u16* out, int R, int C,
                                        int bx, int by, int tx, int ty, bool isbf,
                                        u16 (*tile)[33]) {
    const int c0 = bx * 32, r0 = by * 32;
#pragma unroll
    for (int i = 0; i < 4; i++) {
        const size_t idx = (size_t)(r0 + ty + i * 8) * C + c0 + tx;
        tile[ty + i * 8][tx] = isbf ? ((const u16*)in)[idx]
                                    : f2bf(((const float*)in)[idx]);
    }
    __syncthreads();
#pragma unroll
    for (int i = 0; i < 4; i++)
        out[(size_t)(c0 + ty + i * 8) * R + r0 + tx] = tile[tx][ty + i * 8];
}
__global__ void transpose_fused(const void* __restrict__ Wi, u16* __restrict__ WiT,
                                const void* __restrict__ Wo, u16* __restrict__ WoT,
                                const void* __restrict__ Wd, u16* __restrict__ WdT,
                                const void* __restrict__ Wx, u16* __restrict__ WxT,
                                const int* __restrict__ flag) {
    __shared__ u16 tile[32][33];
    const bool isbf = (*flag != 0);
    const int tx = threadIdx.x, ty = threadIdx.y;   // (32,8)
    int blk = blockIdx.x;
    if (blk < 16384) { tr_tile(Wi, WiT, 2048, 8192, blk % 256, blk / 256, tx, ty, isbf, tile); return; }
    blk -= 16384;
    if (blk < 8192)  { tr_tile(Wo, WoT, 4096, 2048, blk % 64, blk / 64, tx, ty, isbf, tile); return; }
    blk -= 8192;
    if (blk < 512)   { tr_tile(Wd, WdT, 128, 4096, blk % 128, blk / 128, tx, ty, isbf, tile); return; }
    blk -= 512;
    tr_tile(Wx, WxT, 4096, 160, blk % 5, blk / 5, tx, ty, isbf, tile);   // 640 blocks
}

// ---------------- generic bf16 MFMA GEMM:  C[M,N] = A[M,K] * Bt[N,K]^T -------
// Staging: global_load_lds width=16, lane-ordered LDS (no padding).
// MODE 0: bf16 store. MODE 1: flag-aware store (bf16/fp32) for d_out.
// MODE 2: fp32 softplus(acc + bias[col]). MODE 4: fp32 atomicAdd.
template <int BM, int BN, int BK, int WR, int WC, int MT, int NT, int MODE>
__global__ __launch_bounds__(256) void gemm_bt(
    const u16* __restrict__ A, const u16* __restrict__ Bt,
    void* __restrict__ C, const u16* __restrict__ bias,
    const int* __restrict__ oflagp,
    int M, int N, int K)
{
    static_assert(BK == 32, "BK=32 (one 16x16x32 MFMA k-slab)");
    __shared__ u16 As[BM * BK];
    __shared__ u16 Bs[BN * BK];

    const int tid  = threadIdx.x;
    const int lane = tid & 63;
    const int wave = tid >> 6;
    const int wm = wave / WC, wn = wave % WC;

    const int m0 = blockIdx.y * BM;
    const int n0 = blockIdx.x * BN;
    const int Kchunk = K / gridDim.z;
    const int kbeg = blockIdx.z * Kchunk;
    const int kend = kbeg + Kchunk;

    int oflag = 1;
    if constexpr (MODE == 1) oflag = *oflagp;

    f32x4 acc[MT][NT];
#pragma unroll
    for (int mi = 0; mi < MT; mi++)
#pragma unroll
        for (int ni = 0; ni < NT; ni++)
            acc[mi][ni] = (f32x4){0.f, 0.f, 0.f, 0.f};

    const int koff = (lane >> 4) * 8;
    const int arow = wm * MT * 16 + (lane & 15);
    const int brow = wn * NT * 16 + (lane & 15);

    constexpr int CHA = BM * 4;            // 16B chunks in A tile
    constexpr int CHB = BN * 4;

    for (int k0 = kbeg; k0 < kend; k0 += BK) {
        __syncthreads();
#pragma unroll
        for (int it = 0; it < (CHA + 255) / 256; it++) {
            const int c = it * 256 + tid;
            if (CHA % 256 == 0 || c < CHA) {
                const int row = c >> 2, kc = c & 3;
                const u16* gp = &A[(size_t)(m0 + row) * K + k0 + kc * 8];
                __builtin_amdgcn_global_load_lds(
                    (const __attribute__((address_space(1))) void*)gp,
                    (__attribute__((address_space(3))) void*)&As[c * 8], 16, 0, 0);
            }
        }
#pragma unroll
        for (int it = 0; it < (CHB + 255) / 256; it++) {
            const int c = it * 256 + tid;
            if (CHB % 256 == 0 || c < CHB) {
                const int row = c >> 2, kc = c & 3;
                const u16* gp = &Bt[(size_t)(n0 + row) * K + k0 + kc * 8];
                __builtin_amdgcn_global_load_lds(
                    (const __attribute__((address_space(1))) void*)gp,
                    (__attribute__((address_space(3))) void*)&Bs[c * 8], 16, 0, 0);
            }
        }
        __syncthreads();

        bf16x8 af[MT], bfr[NT];
#pragma unroll
        for (int mi = 0; mi < MT; mi++)
            af[mi] = *reinterpret_cast<const bf16x8*>(&As[(arow + mi * 16) * BK + koff]);
#pragma unroll
        for (int ni = 0; ni < NT; ni++)
            bfr[ni] = *reinterpret_cast<const bf16x8*>(&Bs[(brow + ni * 16) * BK + koff]);
#pragma unroll
        for (int mi = 0; mi < MT; mi++)
#pragma unroll
            for (int ni = 0; ni < NT; ni++)
                acc[mi][ni] = __builtin_amdgcn_mfma_f32_16x16x32_bf16(
                    af[mi], bfr[ni], acc[mi][ni], 0, 0, 0);
    }

    const int rb = m0 + wm * MT * 16 + ((lane >> 4) << 2);
    const int cb = n0 + wn * NT * 16 + (lane & 15);
#pragma unroll
    for (int mi = 0; mi < MT; mi++) {
#pragma unroll
        for (int ni = 0; ni < NT; ni++) {
            const int col = cb + ni * 16;
#pragma unroll
            for (int r = 0; r < 4; r++) {
                const int row = rb + mi * 16 + r;
                const float v = acc[mi][ni][r];
                if constexpr (MODE == 0) {
                    ((u16*)C)[(size_t)row * N + col] = f2bf(v);
                } else if constexpr (MODE == 1) {
                    if (oflag) ((u16*)C)[(size_t)row * N + col] = f2bf(v);
                    else       ((float*)C)[(size_t)row * N + col] = v;
                } else if constexpr (MODE == 2) {
                    const float x = v + bf2f(bias[col]);
                    const float sp = (x > 20.f) ? x : log1pf(__expf(x));
                    ((float*)C)[(size_t)row * N + col] = sp;
                } else if constexpr (MODE == 4) {
                    atomicAdd(((float*)C) + (size_t)row * N + col, v);
                }
            }
        }
    }
}

// ---------------- depthwise conv3 + bias + silu -----------------------------
__global__ void conv_silu(const u16* __restrict__ xz, const u16* __restrict__ conv_w,
                          const u16* __restrict__ conv_b, u16* __restrict__ xc) {
    const int idx = blockIdx.x * 256 + threadIdx.x;    // 2048*4096
    const int row = idx >> 12, c = idx & 4095;
    const int l = row & 1023;
    const float w0 = bf2f(conv_w[c * 3 + 0]);
    const float w1 = bf2f(conv_w[c * 3 + 1]);
    const float w2 = bf2f(conv_w[c * 3 + 2]);
    const float x0 = bf2f(xz[(size_t)row * 8192 + c]);
    const float xm = (l > 0)    ? bf2f(xz[(size_t)(row - 1) * 8192 + c]) : 0.f;
    const float xp = (l < 1023) ? bf2f(xz[(size_t)(row + 1) * 8192 + c]) : 0.f;
    float v = w0 * xm + w1 * x0 + w2 * xp + bf2f(conv_b[c]);
    v = v / (1.f + __expf(-v));
    xc[(size_t)row * 4096 + c] = f2bf(v);
}

// ---------------- x_dbl[:, :128] -> bf16 ------------------------------------
__global__ void cvt_dtin(const float* __restrict__ x_dbl, u16* __restrict__ dtin) {
    const int idx = blockIdx.x * 256 + threadIdx.x;    // 2048*128
    const int row = idx >> 7, c = idx & 127;
    dtin[idx] = f2bf(x_dbl[(size_t)row * 160 + c]);
}

// ---------------- S1: per-chunk local scan (h_in = 0), lane = channel -------
// grid (NCHUNK, 16, 2), 256 threads: lane owns all 16 states of one channel.
__global__ __launch_bounds__(256) void scan_p1(
    const float* __restrict__ dt, const u16* __restrict__ xc,
    const float* __restrict__ x_dbl, const u16* __restrict__ A_log,
    float* __restrict__ Parr, u16* __restrict__ xzbase)
{
    __shared__ float Bsm[CLEN][16];
    const int tid = threadIdx.x;
    const int nc = blockIdx.x, cg = blockIdx.y, b = blockIdx.z;
    const int ch = cg * 256 + tid;
    const size_t row0 = (size_t)b * 1024 + nc * CLEN;

    {   // stage B[t][s]: 64 rows x 16 floats; 256 threads x 1 float4
        const int t = tid >> 2, q = tid & 3;
        const float4 v = *(const float4*)&x_dbl[(row0 + t) * 160 + 128 + q * 4];
        *(float4*)&Bsm[t][q * 4] = v;
    }
    __syncthreads();

    float A_s[16], h[16];
#pragma unroll
    for (int s = 0; s < 16; s++) {
        A_s[s] = -__expf(bf2f(A_log[ch * 16 + s]));
        h[s] = 0.f;
    }
    float Sdt = 0.f;

    float dt_v = dt[row0 * 4096 + ch];
    float u_v  = bf2f(xc[row0 * 4096 + ch]);
    for (int t = 0; t < CLEN; t++) {
        const int tn = (t + 1 < CLEN) ? t + 1 : t;
        const float dt_n = dt[(row0 + tn) * 4096 + ch];
        const float u_n  = bf2f(xc[(row0 + tn) * 4096 + ch]);
        const float dtu = dt_v * u_v;
        Sdt += dt_v;
        const f32x4* Brow = (const f32x4*)&Bsm[t][0];
        const f32x4 B0 = Brow[0], B1 = Brow[1], B2 = Brow[2], B3 = Brow[3];
#pragma unroll
        for (int s = 0; s < 16; s++) {
            const float Bs_ = (s < 4 ? B0[s & 3] : s < 8 ? B1[s & 3] : s < 12 ? B2[s & 3] : B3[s & 3]);
            const float dA = __expf(dt_v * A_s[s]);
            h[s] = dA * h[s] + dtu * Bs_;
        }
        dt_v = dt_n; u_v = u_n;
    }
    const int i0 = (((b * NCHUNK + nc) * 4096) + ch) * 16;
#pragma unroll
    for (int s = 0; s < 16; s++) {
        Parr[i0 + s] = __expf(A_s[s] * Sdt);   // prod(exp(dt*A)) = exp(A*sum dt)
        *hloc_ptr(xzbase, i0 + s) = h[s];
    }
}

// ---------------- S2: combine chunk summaries -> h_in -----------------------
__global__ __launch_bounds__(256) void scan_p2(
    const float* __restrict__ Parr, u16* __restrict__ xzbase)
{
    const int tid = threadIdx.x;
    const int lane = tid & 63, wave = tid >> 6;
    const int blk = blockIdx.x;
    const int b = blk >> 8, cg = blk & 255;
    const int c_local = lane & 3, s = lane >> 2;
    const int ch = cg * 16 + wave * 4 + c_local;

    float Pv[NCHUNK], hl[NCHUNK];
#pragma unroll
    for (int c = 0; c < NCHUNK; c++) {
        const int i = (((b * NCHUNK + c) * 4096) + ch) * 16 + s;
        Pv[c] = Parr[i];
        hl[c] = *hloc_ptr(xzbase, i);
    }
    float hin = 0.f;
#pragma unroll
    for (int c = 0; c < NCHUNK; c++) {
        const int i = (((b * NCHUNK + c) * 4096) + ch) * 16 + s;
        *hin_ptr(xzbase, i) = hin;
        hin = Pv[c] * hin + hl[c];
    }
}

// ---------------- S3: rescan with h_in; fused gate; lane = channel ----------
__global__ __launch_bounds__(256) void scan_p3(
    const float* __restrict__ dt, const u16* __restrict__ xc,
    const float* __restrict__ x_dbl, const u16* __restrict__ xz,
    const u16* __restrict__ A_log, const u16* __restrict__ Dp,
    u16* __restrict__ yg, u16* __restrict__ xzbase)
{
    __shared__ float BCs[CLEN][32];   // [t][0..15]=B, [t][16..31]=C
    const int tid = threadIdx.x;
    const int nc = blockIdx.x, cg = blockIdx.y, b = blockIdx.z;
    const int ch = cg * 256 + tid;
    const size_t row0 = (size_t)b * 1024 + nc * CLEN;

#pragma unroll
    for (int it = 0; it < 2; it++) {   // 64 rows x 32 floats; 512 float4
        const int c = it * 256 + tid;
        const int t = c >> 3, q = c & 7;
        const float4 v = *(const float4*)&x_dbl[(row0 + t) * 160 + 128 + q * 4];
        *(float4*)&BCs[t][q * 4] = v;
    }
    __syncthreads();

    float A_s[16], h[16];
    const int i0 = (((b * NCHUNK + nc) * 4096) + ch) * 16;
#pragma unroll
    for (int s = 0; s < 16; s++) {
        A_s[s] = -__expf(bf2f(A_log[ch * 16 + s]));
        h[s] = *hin_ptr(xzbase, i0 + s);
    }
    const float D_ch = bf2f(Dp[ch]);

    float dt_v = dt[row0 * 4096 + ch];
    float u_v  = bf2f(xc[row0 * 4096 + ch]);
    float z_v  = bf2f(xz[row0 * 8192 + 4096 + ch]);
    for (int t = 0; t < CLEN; t++) {
        const int tn = (t + 1 < CLEN) ? t + 1 : t;
        const size_t rn = row0 + tn;
        const float dt_n = dt[rn * 4096 + ch];
        const float u_n  = bf2f(xc[rn * 4096 + ch]);
        const float z_n  = bf2f(xz[rn * 8192 + 4096 + ch]);
        const float dtu = dt_v * u_v;

        const f32x4* Row = (const f32x4*)&BCs[t][0];
        const f32x4 B0 = Row[0], B1 = Row[1], B2 = Row[2], B3 = Row[3];
        const f32x4 C0 = Row[4], C1 = Row[5], C2 = Row[6], C3 = Row[7];

        float y0 = 0.f, y1 = 0.f, y2 = 0.f, y3 = 0.f;
#pragma unroll
        for (int s = 0; s < 16; s++) {
            const float Bs_ = (s < 4 ? B0[s & 3] : s < 8 ? B1[s & 3] : s < 12 ? B2[s & 3] : B3[s & 3]);
            const float Cs_ = (s < 4 ? C0[s & 3] : s < 8 ? C1[s & 3] : s < 12 ? C2[s & 3] : C3[s & 3]);
            const float dA = __expf(dt_v * A_s[s]);
            h[s] = dA * h[s] + dtu * Bs_;
            const float hc = h[s] * Cs_;
            if ((s & 3) == 0) y0 += hc; else if ((s & 3) == 1) y1 += hc;
            else if ((s & 3) == 2) y2 += hc; else y3 += hc;
        }
        const float y = (y0 + y1) + (y2 + y3);
        const float silu_z = z_v / (1.f + __expf(-z_v));
        yg[(row0 + t) * 4096 + ch] = f2bf((y + u_v * D_ch) * silu_z);
        dt_v = dt_n; u_v = u_n; z_v = z_n;
    }
}

extern "C" void kernel_launch(void* const* d_in, const int* in_sizes, int n_in,
                              void* d_out, int out_size, void* d_ws, size_t ws_size,
                              hipStream_t stream)
{
    const void* x_raw      = d_in[0];   // (2,1024,2048)
    const void* W_in_raw   = d_in[1];   // (2048,8192)
    const void* conv_w_raw = d_in[2];   // (4096,1,3)
    const void* conv_b_raw = d_in[3];   // (4096)
    const void* W_x_raw    = d_in[4];   // (4096,160)
    const void* W_dt_raw   = d_in[5];   // (128,4096)
    const void* b_dt_raw   = d_in[6];   // (4096)
    const void* A_log_raw  = d_in[7];   // (4096,16)
    const void* D_raw      = d_in[8];   // (4096)
    const void* W_out_raw  = d_in[9];   // (4096,2048)

    char* ws = (char*)d_ws;
    size_t off = 0;
    auto alloc = [&](size_t bytes) { char* p = ws + off; off += (bytes + 255) & ~(size_t)255; return p; };
    int*   flag   = (int*)  alloc(4);
    u16*   W_inT  = (u16*)  alloc(8192ULL * 2048 * 2);   // 32 MB (aliased by dt fp32 after K1)
    u16*   W_outT = (u16*)  alloc(2048ULL * 4096 * 2);   // 16 MB
    u16*   W_dtT  = (u16*)  alloc(4096ULL * 128 * 2);    // 1 MB
    u16*   W_xT   = (u16*)  alloc(160ULL * 4096 * 2);    // 1.25 MB
    u16*   xz     = (u16*)  alloc(2048ULL * 8192 * 2);   // 32 MB (xp half reused as h_loc/h_in)
    u16*   xc     = (u16*)  alloc(2048ULL * 4096 * 2);   // 16 MB
    float* x_dbl  = (float*)alloc(2048ULL * 160 * 4);    // 1.25 MB
    u16*   dtin   = (u16*)  alloc(2048ULL * 128 * 2);    // 0.5 MB
    u16*   yg     = (u16*)  alloc(2048ULL * 4096 * 2);   // 16 MB
    u16*   xcan   = (u16*)  alloc(2048ULL * 2048 * 2);   // 8 MB (reused as Parr fp32)
    u16*   cw_c   = (u16*)  alloc(12288 * 2);
    u16*   cb_c   = (u16*)  alloc(4096 * 2);
    u16*   bdt_c  = (u16*)  alloc(4096 * 2);
    u16*   Alog_c = (u16*)  alloc(65536 * 2);
    u16*   D_c    = (u16*)  alloc(4096 * 2);
    float* dtv    = (float*)W_inT;   // alias: W_inT dead after K1 (32 MB exact)
    float* Parr   = (float*)xcan;    // alias: xcan dead after K1 (8 MB exact)

    // D) dtype flag, fused canonicalize + x_dbl zero
    detect_dtype<<<1, 256, 0, stream>>>((const u16*)x_raw, flag);
    cvt_fused<<<16384 + 48 + 16 + 16 + 256 + 16 + 1280, 256, 0, stream>>>(
        x_raw, xcan, conv_w_raw, cw_c, conv_b_raw, cb_c, b_dt_raw, bdt_c,
        A_log_raw, Alog_c, D_raw, D_c, x_dbl, flag);

    // T) fused transposes
    transpose_fused<<<16384 + 8192 + 512 + 640, dim3(32, 8), 0, stream>>>(
        W_in_raw, W_inT, W_out_raw, W_outT, W_dt_raw, W_dtT, W_x_raw, W_xT, flag);

    // K1: xz = x @ W_in   (M=2048, N=8192, K=2048)
    gemm_bt<128, 128, 32, 2, 2, 4, 4, 0>
        <<<dim3(8192 / 128, 2048 / 128, 1), 256, 0, stream>>>(xcan, W_inT, xz, nullptr, nullptr, 2048, 8192, 2048);

    // K2: conv + bias + silu
    conv_silu<<<(2048 * 4096) / 256, 256, 0, stream>>>(xz, cw_c, cb_c, xc);

    // K3: x_dbl = xc @ W_x   (split-K=8, atomic fp32; x_dbl zeroed in cvt_fused)
    gemm_bt<64, 160, 32, 4, 1, 1, 10, 4>
        <<<dim3(1, 2048 / 64, 8), 256, 0, stream>>>(xc, W_xT, x_dbl, nullptr, nullptr, 2048, 160, 4096);

    cvt_dtin<<<(2048 * 128) / 256, 256, 0, stream>>>(x_dbl, dtin);

    // K4: dt = softplus(dtin @ W_dt + b_dt)   (fp32 out)
    gemm_bt<128, 128, 32, 2, 2, 4, 4, 2>
        <<<dim3(4096 / 128, 2048 / 128, 1), 256, 0, stream>>>(dtin, W_dtT, dtv, bdt_c, nullptr, 2048, 4096, 128);

    // S1/S2/S3: chunked selective scan (lane=channel) with fused gating
    scan_p1<<<dim3(NCHUNK, 16, 2), 256, 0, stream>>>(dtv, xc, x_dbl, Alog_c, Parr, xz);
    scan_p2<<<512, 256, 0, stream>>>(Parr, xz);
    scan_p3<<<dim3(NCHUNK, 16, 2), 256, 0, stream>>>(dtv, xc, x_dbl, xz, Alog_c, D_c, yg, xz);

    // K6: out = yg @ W_out   (M=2048, N=2048, K=4096), flag-aware store
    gemm_bt<128, 128, 32, 2, 2, 4, 4, 1>
        <<<dim3(2048 / 128, 2048 / 128, 1), 256, 0, stream>>>(yg, W_outT, d_out, nullptr, flag, 2048, 2048, 4096);
}

// Round 8
// 528.339 us; speedup vs baseline: 2.0051x; 1.0396x over previous
//
#include <hip/hip_runtime.h>
#include <hip/hip_bf16.h>

// Selective SSM (Mamba-style): B=2, L=1024, H=2048, E=2 -> d=4096, S=16, R=128.
// Round 8: (a) XOR chunk-swizzle in gemm_bt LDS tiles: fragment ds_read_b128
// goes 8-way -> 2-way bank aliasing (free, m136) with global_load_lds intact;
// (b) K6 retiled 128x128 -> 64x128 (256 -> 512 blocks = 2 blocks/CU).

using u16 = unsigned short;
typedef __bf16 bf16x8 __attribute__((ext_vector_type(8)));
typedef float f32x4 __attribute__((ext_vector_type(4)));

#define NCHUNK 16
#define CLEN   64
// chunk swizzle: quad j of row r lives at chunk r*4 + (j ^ ((r>>1)&3))
#define SWZ(row, q) ((q) ^ (((row) >> 1) & 3))

__device__ __forceinline__ float bf2f(u16 u) {
    union { unsigned int i; float f; } v; v.i = ((unsigned int)u) << 16; return v.f;
}
__device__ __forceinline__ u16 f2bf(float f) {
    union { float f; unsigned int i; } v; v.f = f;
    unsigned int x = v.i;
    return (u16)((x + 0x7FFFu + ((x >> 16) & 1u)) >> 16);   // RNE
}

// fp32 scratch carved out of the dead xp-column half of xz (rows x 8192 u16;
// cols 0..4095 dead after conv). h_loc: rows 0..1023, h_in: rows 1024..2047.
__device__ __forceinline__ float* hloc_ptr(u16* xzbase, int i) {
    return reinterpret_cast<float*>(xzbase + (size_t)(i >> 11) * 8192) + (i & 2047);
}
__device__ __forceinline__ float* hin_ptr(u16* xzbase, int i) {
    return reinterpret_cast<float*>(xzbase + (size_t)((i >> 11) + 1024) * 8192) + (i & 2047);
}

// ---------------- dtype detection -------------------------------------------
__global__ void detect_dtype(const u16* __restrict__ xraw, int* __restrict__ flag) {
    __shared__ int cnt[256];
    const int tid = threadIdx.x;
    int plausible = 0;
    for (int i = tid; i < 4096; i += 256) {
        const u16 v = xraw[2 * i];
        const int e = (v >> 7) & 0xFF;
        plausible += (e >= 100 && e <= 145) ? 1 : 0;
    }
    cnt[tid] = plausible;
    __syncthreads();
    for (int s = 128; s > 0; s >>= 1) {
        if (tid < s) cnt[tid] += cnt[tid + s];
        __syncthreads();
    }
    if (tid == 0) *flag = (cnt[0] > 2458) ? 1 : 0;
}

// ---------------- fused canonicalize (6 tensors) + x_dbl zero ---------------
__device__ __forceinline__ void cvt_seg(const void* src, u16* dst, int i,
                                        bool isbf) {
    dst[i] = isbf ? ((const u16*)src)[i] : f2bf(((const float*)src)[i]);
}
__global__ void cvt_fused(const void* __restrict__ x_raw, u16* __restrict__ xcan,
                          const void* __restrict__ cw_raw, u16* __restrict__ cw_c,
                          const void* __restrict__ cb_raw, u16* __restrict__ cb_c,
                          const void* __restrict__ bdt_raw, u16* __restrict__ bdt_c,
                          const void* __restrict__ Alog_raw, u16* __restrict__ Alog_c,
                          const void* __restrict__ D_raw, u16* __restrict__ D_c,
                          float* __restrict__ x_dbl,
                          const int* __restrict__ flag) {
    const bool isbf = (*flag != 0);
    int blk = blockIdx.x;
    const int tid = threadIdx.x;
    if (blk < 16384) { cvt_seg(x_raw, xcan, blk * 256 + tid, isbf); return; }
    blk -= 16384;
    if (blk < 48)  { cvt_seg(cw_raw, cw_c, blk * 256 + tid, isbf); return; }
    blk -= 48;
    if (blk < 16)  { cvt_seg(cb_raw, cb_c, blk * 256 + tid, isbf); return; }
    blk -= 16;
    if (blk < 16)  { cvt_seg(bdt_raw, bdt_c, blk * 256 + tid, isbf); return; }
    blk -= 16;
    if (blk < 256) { cvt_seg(Alog_raw, Alog_c, blk * 256 + tid, isbf); return; }
    blk -= 256;
    if (blk < 16)  { cvt_seg(D_raw, D_c, blk * 256 + tid, isbf); return; }
    blk -= 16;
    x_dbl[blk * 256 + tid] = 0.f;       // 1280 blocks: zero 2048*160 fp32
}

// ---------------- fused flag-aware transposes (4 tensors) -------------------
__device__ __forceinline__ void tr_tile(const void* in, u16* out, int R, int C,
                                        int bx, int by, int tx, int ty, bool isbf,
                                        u16 (*tile)[33]) {
    const int c0 = bx * 32, r0 = by * 32;
#pragma unroll
    for (int i = 0; i < 4; i++) {
        const size_t idx = (size_t)(r0 + ty + i * 8) * C + c0 + tx;
        tile[ty + i * 8][tx] = isbf ? ((const u16*)in)[idx]
                                    : f2bf(((const float*)in)[idx]);
    }
    __syncthreads();
#pragma unroll
    for (int i = 0; i < 4; i++)
        out[(size_t)(c0 + ty + i * 8) * R + r0 + tx] = tile[tx][ty + i * 8];
}
__global__ void transpose_fused(const void* __restrict__ Wi, u16* __restrict__ WiT,
                                const void* __restrict__ Wo, u16* __restrict__ WoT,
                                const void* __restrict__ Wd, u16* __restrict__ WdT,
                                const void* __restrict__ Wx, u16* __restrict__ WxT,
                                const int* __restrict__ flag) {
    __shared__ u16 tile[32][33];
    const bool isbf = (*flag != 0);
    const int tx = threadIdx.x, ty = threadIdx.y;   // (32,8)
    int blk = blockIdx.x;
    if (blk < 16384) { tr_tile(Wi, WiT, 2048, 8192, blk % 256, blk / 256, tx, ty, isbf, tile); return; }
    blk -= 16384;
    if (blk < 8192)  { tr_tile(Wo, WoT, 4096, 2048, blk % 64, blk / 64, tx, ty, isbf, tile); return; }
    blk -= 8192;
    if (blk < 512)   { tr_tile(Wd, WdT, 128, 4096, blk % 128, blk / 128, tx, ty, isbf, tile); return; }
    blk -= 512;
    tr_tile(Wx, WxT, 4096, 160, blk % 5, blk / 5, tx, ty, isbf, tile);   // 640 blocks
}

// ---------------- generic bf16 MFMA GEMM:  C[M,N] = A[M,K] * Bt[N,K]^T -------
// Staging: global_load_lds width=16, lane-ordered LDS + XOR chunk swizzle.
// MODE 0: bf16 store. MODE 1: flag-aware store (bf16/fp32) for d_out.
// MODE 2: fp32 softplus(acc + bias[col]). MODE 4: fp32 atomicAdd.
template <int BM, int BN, int BK, int WR, int WC, int MT, int NT, int MODE>
__global__ __launch_bounds__(256) void gemm_bt(
    const u16* __restrict__ A, const u16* __restrict__ Bt,
    void* __restrict__ C, const u16* __restrict__ bias,
    const int* __restrict__ oflagp,
    int M, int N, int K)
{
    static_assert(BK == 32, "BK=32 (one 16x16x32 MFMA k-slab)");
    __shared__ u16 As[BM * BK];
    __shared__ u16 Bs[BN * BK];

    const int tid  = threadIdx.x;
    const int lane = tid & 63;
    const int wave = tid >> 6;
    const int wm = wave / WC, wn = wave % WC;

    const int m0 = blockIdx.y * BM;
    const int n0 = blockIdx.x * BN;
    const int Kchunk = K / gridDim.z;
    const int kbeg = blockIdx.z * Kchunk;
    const int kend = kbeg + Kchunk;

    int oflag = 1;
    if constexpr (MODE == 1) oflag = *oflagp;

    f32x4 acc[MT][NT];
#pragma unroll
    for (int mi = 0; mi < MT; mi++)
#pragma unroll
        for (int ni = 0; ni < NT; ni++)
            acc[mi][ni] = (f32x4){0.f, 0.f, 0.f, 0.f};

    const int q = lane >> 4;               // k-quad this lane consumes
    const int arow = wm * MT * 16 + (lane & 15);
    const int brow = wn * NT * 16 + (lane & 15);

    constexpr int CHA = BM * 4;            // 16B chunks in A tile
    constexpr int CHB = BN * 4;

    for (int k0 = kbeg; k0 < kend; k0 += BK) {
        __syncthreads();
        // async stage A tile: chunk c holds global quad (c&3)^((row>>1)&3)
#pragma unroll
        for (int it = 0; it < (CHA + 255) / 256; it++) {
            const int c = it * 256 + tid;
            if (CHA % 256 == 0 || c < CHA) {
                const int row = c >> 2, kc = SWZ(row, c & 3);
                const u16* gp = &A[(size_t)(m0 + row) * K + k0 + kc * 8];
                __builtin_amdgcn_global_load_lds(
                    (const __attribute__((address_space(1))) void*)gp,
                    (__attribute__((address_space(3))) void*)&As[c * 8], 16, 0, 0);
            }
        }
#pragma unroll
        for (int it = 0; it < (CHB + 255) / 256; it++) {
            const int c = it * 256 + tid;
            if (CHB % 256 == 0 || c < CHB) {
                const int row = c >> 2, kc = SWZ(row, c & 3);
                const u16* gp = &Bt[(size_t)(n0 + row) * K + k0 + kc * 8];
                __builtin_amdgcn_global_load_lds(
                    (const __attribute__((address_space(1))) void*)gp,
                    (__attribute__((address_space(3))) void*)&Bs[c * 8], 16, 0, 0);
            }
        }
        __syncthreads();

        bf16x8 af[MT], bfr[NT];
#pragma unroll
        for (int mi = 0; mi < MT; mi++) {
            const int row = arow + mi * 16;
            af[mi] = *reinterpret_cast<const bf16x8*>(&As[row * BK + SWZ(row, q) * 8]);
        }
#pragma unroll
        for (int ni = 0; ni < NT; ni++) {
            const int row = brow + ni * 16;
            bfr[ni] = *reinterpret_cast<const bf16x8*>(&Bs[row * BK + SWZ(row, q) * 8]);
        }
#pragma unroll
        for (int mi = 0; mi < MT; mi++)
#pragma unroll
            for (int ni = 0; ni < NT; ni++)
                acc[mi][ni] = __builtin_amdgcn_mfma_f32_16x16x32_bf16(
                    af[mi], bfr[ni], acc[mi][ni], 0, 0, 0);
    }

    const int rb = m0 + wm * MT * 16 + ((lane >> 4) << 2);
    const int cb = n0 + wn * NT * 16 + (lane & 15);
#pragma unroll
    for (int mi = 0; mi < MT; mi++) {
#pragma unroll
        for (int ni = 0; ni < NT; ni++) {
            const int col = cb + ni * 16;
#pragma unroll
            for (int r = 0; r < 4; r++) {
                const int row = rb + mi * 16 + r;
                const float v = acc[mi][ni][r];
                if constexpr (MODE == 0) {
                    ((u16*)C)[(size_t)row * N + col] = f2bf(v);
                } else if constexpr (MODE == 1) {
                    if (oflag) ((u16*)C)[(size_t)row * N + col] = f2bf(v);
                    else       ((float*)C)[(size_t)row * N + col] = v;
                } else if constexpr (MODE == 2) {
                    const float x = v + bf2f(bias[col]);
                    const float sp = (x > 20.f) ? x : log1pf(__expf(x));
                    ((float*)C)[(size_t)row * N + col] = sp;
                } else if constexpr (MODE == 4) {
                    atomicAdd(((float*)C) + (size_t)row * N + col, v);
                }
            }
        }
    }
}

// ---------------- depthwise conv3 + bias + silu -----------------------------
__global__ void conv_silu(const u16* __restrict__ xz, const u16* __restrict__ conv_w,
                          const u16* __restrict__ conv_b, u16* __restrict__ xc) {
    const int idx = blockIdx.x * 256 + threadIdx.x;    // 2048*4096
    const int row = idx >> 12, c = idx & 4095;
    const int l = row & 1023;
    const float w0 = bf2f(conv_w[c * 3 + 0]);
    const float w1 = bf2f(conv_w[c * 3 + 1]);
    const float w2 = bf2f(conv_w[c * 3 + 2]);
    const float x0 = bf2f(xz[(size_t)row * 8192 + c]);
    const float xm = (l > 0)    ? bf2f(xz[(size_t)(row - 1) * 8192 + c]) : 0.f;
    const float xp = (l < 1023) ? bf2f(xz[(size_t)(row + 1) * 8192 + c]) : 0.f;
    float v = w0 * xm + w1 * x0 + w2 * xp + bf2f(conv_b[c]);
    v = v / (1.f + __expf(-v));
    xc[(size_t)row * 4096 + c] = f2bf(v);
}

// ---------------- x_dbl[:, :128] -> bf16 ------------------------------------
__global__ void cvt_dtin(const float* __restrict__ x_dbl, u16* __restrict__ dtin) {
    const int idx = blockIdx.x * 256 + threadIdx.x;    // 2048*128
    const int row = idx >> 7, c = idx & 127;
    dtin[idx] = f2bf(x_dbl[(size_t)row * 160 + c]);
}

// ---------------- S1: per-chunk local scan (h_in = 0), lane = channel -------
// grid (NCHUNK, 16, 2), 256 threads: lane owns all 16 states of one channel.
__global__ __launch_bounds__(256) void scan_p1(
    const float* __restrict__ dt, const u16* __restrict__ xc,
    const float* __restrict__ x_dbl, const u16* __restrict__ A_log,
    float* __restrict__ Parr, u16* __restrict__ xzbase)
{
    __shared__ float Bsm[CLEN][16];
    const int tid = threadIdx.x;
    const int nc = blockIdx.x, cg = blockIdx.y, b = blockIdx.z;
    const int ch = cg * 256 + tid;
    const size_t row0 = (size_t)b * 1024 + nc * CLEN;

    {   // stage B[t][s]: 64 rows x 16 floats; 256 threads x 1 float4
        const int t = tid >> 2, q = tid & 3;
        const float4 v = *(const float4*)&x_dbl[(row0 + t) * 160 + 128 + q * 4];
        *(float4*)&Bsm[t][q * 4] = v;
    }
    __syncthreads();

    float A_s[16], h[16];
#pragma unroll
    for (int s = 0; s < 16; s++) {
        A_s[s] = -__expf(bf2f(A_log[ch * 16 + s]));
        h[s] = 0.f;
    }
    float Sdt = 0.f;

    float dt_v = dt[row0 * 4096 + ch];
    float u_v  = bf2f(xc[row0 * 4096 + ch]);
    for (int t = 0; t < CLEN; t++) {
        const int tn = (t + 1 < CLEN) ? t + 1 : t;
        const float dt_n = dt[(row0 + tn) * 4096 + ch];
        const float u_n  = bf2f(xc[(row0 + tn) * 4096 + ch]);
        const float dtu = dt_v * u_v;
        Sdt += dt_v;
        const f32x4* Brow = (const f32x4*)&Bsm[t][0];
        const f32x4 B0 = Brow[0], B1 = Brow[1], B2 = Brow[2], B3 = Brow[3];
#pragma unroll
        for (int s = 0; s < 16; s++) {
            const float Bs_ = (s < 4 ? B0[s & 3] : s < 8 ? B1[s & 3] : s < 12 ? B2[s & 3] : B3[s & 3]);
            const float dA = __expf(dt_v * A_s[s]);
            h[s] = dA * h[s] + dtu * Bs_;
        }
        dt_v = dt_n; u_v = u_n;
    }
    const int i0 = (((b * NCHUNK + nc) * 4096) + ch) * 16;
#pragma unroll
    for (int s = 0; s < 16; s++) {
        Parr[i0 + s] = __expf(A_s[s] * Sdt);   // prod(exp(dt*A)) = exp(A*sum dt)
        *hloc_ptr(xzbase, i0 + s) = h[s];
    }
}

// ---------------- S2: combine chunk summaries -> h_in -----------------------
__global__ __launch_bounds__(256) void scan_p2(
    const float* __restrict__ Parr, u16* __restrict__ xzbase)
{
    const int tid = threadIdx.x;
    const int lane = tid & 63, wave = tid >> 6;
    const int blk = blockIdx.x;
    const int b = blk >> 8, cg = blk & 255;
    const int c_local = lane & 3, s = lane >> 2;
    const int ch = cg * 16 + wave * 4 + c_local;

    float Pv[NCHUNK], hl[NCHUNK];
#pragma unroll
    for (int c = 0; c < NCHUNK; c++) {
        const int i = (((b * NCHUNK + c) * 4096) + ch) * 16 + s;
        Pv[c] = Parr[i];
        hl[c] = *hloc_ptr(xzbase, i);
    }
    float hin = 0.f;
#pragma unroll
    for (int c = 0; c < NCHUNK; c++) {
        const int i = (((b * NCHUNK + c) * 4096) + ch) * 16 + s;
        *hin_ptr(xzbase, i) = hin;
        hin = Pv[c] * hin + hl[c];
    }
}

// ---------------- S3: rescan with h_in; fused gate; lane = channel ----------
__global__ __launch_bounds__(256) void scan_p3(
    const float* __restrict__ dt, const u16* __restrict__ xc,
    const float* __restrict__ x_dbl, const u16* __restrict__ xz,
    const u16* __restrict__ A_log, const u16* __restrict__ Dp,
    u16* __restrict__ yg, u16* __restrict__ xzbase)
{
    __shared__ float BCs[CLEN][32];   // [t][0..15]=B, [t][16..31]=C
    const int tid = threadIdx.x;
    const int nc = blockIdx.x, cg = blockIdx.y, b = blockIdx.z;
    const int ch = cg * 256 + tid;
    const size_t row0 = (size_t)b * 1024 + nc * CLEN;

#pragma unroll
    for (int it = 0; it < 2; it++) {   // 64 rows x 32 floats; 512 float4
        const int c = it * 256 + tid;
        const int t = c >> 3, q = c & 7;
        const float4 v = *(const float4*)&x_dbl[(row0 + t) * 160 + 128 + q * 4];
        *(float4*)&BCs[t][q * 4] = v;
    }
    __syncthreads();

    float A_s[16], h[16];
    const int i0 = (((b * NCHUNK + nc) * 4096) + ch) * 16;
#pragma unroll
    for (int s = 0; s < 16; s++) {
        A_s[s] = -__expf(bf2f(A_log[ch * 16 + s]));
        h[s] = *hin_ptr(xzbase, i0 + s);
    }
    const float D_ch = bf2f(Dp[ch]);

    float dt_v = dt[row0 * 4096 + ch];
    float u_v  = bf2f(xc[row0 * 4096 + ch]);
    float z_v  = bf2f(xz[row0 * 8192 + 4096 + ch]);
    for (int t = 0; t < CLEN; t++) {
        const int tn = (t + 1 < CLEN) ? t + 1 : t;
        const size_t rn = row0 + tn;
        const float dt_n = dt[rn * 4096 + ch];
        const float u_n  = bf2f(xc[rn * 4096 + ch]);
        const float z_n  = bf2f(xz[rn * 8192 + 4096 + ch]);
        const float dtu = dt_v * u_v;

        const f32x4* Row = (const f32x4*)&BCs[t][0];
        const f32x4 B0 = Row[0], B1 = Row[1], B2 = Row[2], B3 = Row[3];
        const f32x4 C0 = Row[4], C1 = Row[5], C2 = Row[6], C3 = Row[7];

        float y0 = 0.f, y1 = 0.f, y2 = 0.f, y3 = 0.f;
#pragma unroll
        for (int s = 0; s < 16; s++) {
            const float Bs_ = (s < 4 ? B0[s & 3] : s < 8 ? B1[s & 3] : s < 12 ? B2[s & 3] : B3[s & 3]);
            const float Cs_ = (s < 4 ? C0[s & 3] : s < 8 ? C1[s & 3] : s < 12 ? C2[s & 3] : C3[s & 3]);
            const float dA = __expf(dt_v * A_s[s]);
            h[s] = dA * h[s] + dtu * Bs_;
            const float hc = h[s] * Cs_;
            if ((s & 3) == 0) y0 += hc; else if ((s & 3) == 1) y1 += hc;
            else if ((s & 3) == 2) y2 += hc; else y3 += hc;
        }
        const float y = (y0 + y1) + (y2 + y3);
        const float silu_z = z_v / (1.f + __expf(-z_v));
        yg[(row0 + t) * 4096 + ch] = f2bf((y + u_v * D_ch) * silu_z);
        dt_v = dt_n; u_v = u_n; z_v = z_n;
    }
}

extern "C" void kernel_launch(void* const* d_in, const int* in_sizes, int n_in,
                              void* d_out, int out_size, void* d_ws, size_t ws_size,
                              hipStream_t stream)
{
    const void* x_raw      = d_in[0];   // (2,1024,2048)
    const void* W_in_raw   = d_in[1];   // (2048,8192)
    const void* conv_w_raw = d_in[2];   // (4096,1,3)
    const void* conv_b_raw = d_in[3];   // (4096)
    const void* W_x_raw    = d_in[4];   // (4096,160)
    const void* W_dt_raw   = d_in[5];   // (128,4096)
    const void* b_dt_raw   = d_in[6];   // (4096)
    const void* A_log_raw  = d_in[7];   // (4096,16)
    const void* D_raw      = d_in[8];   // (4096)
    const void* W_out_raw  = d_in[9];   // (4096,2048)

    char* ws = (char*)d_ws;
    size_t off = 0;
    auto alloc = [&](size_t bytes) { char* p = ws + off; off += (bytes + 255) & ~(size_t)255; return p; };
    int*   flag   = (int*)  alloc(4);
    u16*   W_inT  = (u16*)  alloc(8192ULL * 2048 * 2);   // 32 MB (aliased by dt fp32 after K1)
    u16*   W_outT = (u16*)  alloc(2048ULL * 4096 * 2);   // 16 MB
    u16*   W_dtT  = (u16*)  alloc(4096ULL * 128 * 2);    // 1 MB
    u16*   W_xT   = (u16*)  alloc(160ULL * 4096 * 2);    // 1.25 MB
    u16*   xz     = (u16*)  alloc(2048ULL * 8192 * 2);   // 32 MB (xp half reused as h_loc/h_in)
    u16*   xc     = (u16*)  alloc(2048ULL * 4096 * 2);   // 16 MB
    float* x_dbl  = (float*)alloc(2048ULL * 160 * 4);    // 1.25 MB
    u16*   dtin   = (u16*)  alloc(2048ULL * 128 * 2);    // 0.5 MB
    u16*   yg     = (u16*)  alloc(2048ULL * 4096 * 2);   // 16 MB
    u16*   xcan   = (u16*)  alloc(2048ULL * 2048 * 2);   // 8 MB (reused as Parr fp32)
    u16*   cw_c   = (u16*)  alloc(12288 * 2);
    u16*   cb_c   = (u16*)  alloc(4096 * 2);
    u16*   bdt_c  = (u16*)  alloc(4096 * 2);
    u16*   Alog_c = (u16*)  alloc(65536 * 2);
    u16*   D_c    = (u16*)  alloc(4096 * 2);
    float* dtv    = (float*)W_inT;   // alias: W_inT dead after K1 (32 MB exact)
    float* Parr   = (float*)xcan;    // alias: xcan dead after K1 (8 MB exact)

    // D) dtype flag, fused canonicalize + x_dbl zero
    detect_dtype<<<1, 256, 0, stream>>>((const u16*)x_raw, flag);
    cvt_fused<<<16384 + 48 + 16 + 16 + 256 + 16 + 1280, 256, 0, stream>>>(
        x_raw, xcan, conv_w_raw, cw_c, conv_b_raw, cb_c, b_dt_raw, bdt_c,
        A_log_raw, Alog_c, D_raw, D_c, x_dbl, flag);

    // T) fused transposes
    transpose_fused<<<16384 + 8192 + 512 + 640, dim3(32, 8), 0, stream>>>(
        W_in_raw, W_inT, W_out_raw, W_outT, W_dt_raw, W_dtT, W_x_raw, W_xT, flag);

    // K1: xz = x @ W_in   (M=2048, N=8192, K=2048)
    gemm_bt<128, 128, 32, 2, 2, 4, 4, 0>
        <<<dim3(8192 / 128, 2048 / 128, 1), 256, 0, stream>>>(xcan, W_inT, xz, nullptr, nullptr, 2048, 8192, 2048);

    // K2: conv + bias + silu
    conv_silu<<<(2048 * 4096) / 256, 256, 0, stream>>>(xz, cw_c, cb_c, xc);

    // K3: x_dbl = xc @ W_x   (split-K=8, atomic fp32; x_dbl zeroed in cvt_fused)
    gemm_bt<64, 160, 32, 4, 1, 1, 10, 4>
        <<<dim3(1, 2048 / 64, 8), 256, 0, stream>>>(xc, W_xT, x_dbl, nullptr, nullptr, 2048, 160, 4096);

    cvt_dtin<<<(2048 * 128) / 256, 256, 0, stream>>>(x_dbl, dtin);

    // K4: dt = softplus(dtin @ W_dt + b_dt)   (fp32 out)
    gemm_bt<128, 128, 32, 2, 2, 4, 4, 2>
        <<<dim3(4096 / 128, 2048 / 128, 1), 256, 0, stream>>>(dtin, W_dtT, dtv, bdt_c, nullptr, 2048, 4096, 128);

    // S1/S2/S3: chunked selective scan (lane=channel) with fused gating
    scan_p1<<<dim3(NCHUNK, 16, 2), 256, 0, stream>>>(dtv, xc, x_dbl, Alog_c, Parr, xz);
    scan_p2<<<512, 256, 0, stream>>>(Parr, xz);
    scan_p3<<<dim3(NCHUNK, 16, 2), 256, 0, stream>>>(dtv, xc, x_dbl, xz, Alog_c, D_c, yg, xz);

    // K6: out = yg @ W_out   (M=2048, N=2048, K=4096), 64x128 tile -> 512 blocks
    gemm_bt<64, 128, 32, 2, 2, 2, 4, 1>
        <<<dim3(2048 / 128, 2048 / 64, 1), 256, 0, stream>>>(yg, W_outT, d_out, nullptr, flag, 2048, 2048, 4096);
}